// Round 13
// baseline (936.146 us; speedup 1.0000x reference)
//
#include <hip/hip_runtime.h>
#include <hip/hip_bf16.h>

#define B_ 256
#define T_ 512
#define IN_ 202
#define HID_ 100
#define K_ 19

typedef __attribute__((ext_vector_type(8))) short short8v;
typedef __attribute__((ext_vector_type(4))) float f32x4;

__device__ __forceinline__ float rl_f(float v, int l) {
  return __int_as_float(__builtin_amdgcn_readlane(__float_as_int(v), l));
}

// ---------------- K0a: split [wf;wb] (200x202) into 3 exact bf16 planes, padded to 224x224.
__global__ __launch_bounds__(256, 1) void k_wprep(
    const float* __restrict__ wf, const float* __restrict__ wb,
    unsigned short* __restrict__ w3) {
  int idx = blockIdx.x * 256 + threadIdx.x;
  if (idx >= 224 * 224) return;
  int c = idx / 224, k = idx - (idx / 224) * 224;
  float v = 0.f;
  if (k < IN_) {
    if (c < 100) v = wf[c * IN_ + k];
    else if (c < 200) v = wb[(c - 100) * IN_ + k];
  }
  unsigned u0 = __float_as_uint(v) & 0xffff0000u;
  float r1 = v - __uint_as_float(u0);
  unsigned u1 = __float_as_uint(r1) & 0xffff0000u;
  float r2 = r1 - __uint_as_float(u1);
  w3[idx] = (unsigned short)(u0 >> 16);
  w3[50176 + idx] = (unsigned short)(u1 >> 16);
  w3[100352 + idx] = (unsigned short)(__float_as_uint(r2) >> 16);
}

// ---------------- K0b: split w_hh (2 dirs, 100x100) into 2 bf16 planes, padded to 112x128.
// wh[((dir*2+plane)*112 + col)*128 + k]; zeros outside col<100,k<100.
__global__ __launch_bounds__(256, 1) void k_whprep(
    const float* __restrict__ whf, const float* __restrict__ whb,
    unsigned short* __restrict__ wh) {
  int idx = blockIdx.x * 256 + threadIdx.x;
  if (idx >= 4 * 112 * 128) return;
  int k = idx & 127;
  int rest = idx >> 7;
  int c = rest % 112;
  int dp = rest / 112;  // dir*2 + plane
  int dir = dp >> 1, p = dp & 1;
  float v = 0.f;
  if (c < 100 && k < 100) v = (dir ? whb : whf)[c * 100 + k];
  unsigned u0 = __float_as_uint(v) & 0xffff0000u;
  float r1 = v - __uint_as_float(u0);
  unsigned u1 = __float_as_uint(r1) & 0xffff0000u;
  wh[idx] = p ? (unsigned short)(u1 >> 16) : (unsigned short)(u0 >> 16);
}

// ---------------- K1: pre = x . [wf;wb]^T + bias via bf16-split MFMA (round-10 proven).
__global__ __launch_bounds__(256, 2) void k_ih(
    const float* __restrict__ x, const unsigned short* __restrict__ w3,
    const float* __restrict__ bif, const float* __restrict__ bhf,
    const float* __restrict__ bib, const float* __restrict__ bhb,
    float* __restrict__ pre) {
  __shared__ float xs[256 * 36];
  __shared__ float bsum[224];
  int tid = threadIdx.x;
  int wv = tid >> 6, l = tid & 63;
  long row0 = (long)blockIdx.x * 256;
  for (int u = tid; u < 224; u += 256) {
    float bv = 0.f;
    if (u < 100) bv = bif[u] + bhf[u];
    else if (u < 200) bv = bib[u - 100] + bhb[u - 100];
    bsum[u] = bv;
  }
  int lr = l & 15;
  int kq = l >> 4;
  for (int g = 0; g < 2; g++) {
    f32x4 acc[4][7];
#pragma unroll
    for (int m = 0; m < 4; m++)
#pragma unroll
      for (int n = 0; n < 7; n++) acc[m][n] = (f32x4){0.f, 0.f, 0.f, 0.f};
    for (int ck = 0; ck < 7; ck++) {
      int k0 = ck * 32;
      __syncthreads();
#pragma unroll
      for (int i = 0; i < 16; i++) {
        int u = tid + i * 256;
        int r = u >> 4, kp = u & 15;
        int gk = k0 + 2 * kp;
        float2 v = make_float2(0.f, 0.f);
        if (gk < IN_) v = *(const float2*)(x + (row0 + r) * IN_ + gk);
        *(float2*)(&xs[r * 36 + 2 * kp]) = v;
      }
      __syncthreads();
      short8v A0[4], A1[4], A2[4];
#pragma unroll
      for (int m = 0; m < 4; m++) {
        const float* ap = &xs[(wv * 64 + m * 16 + lr) * 36 + kq * 8];
        float4 fa = *(const float4*)(ap);
        float4 fb = *(const float4*)(ap + 4);
        float f[8] = {fa.x, fa.y, fa.z, fa.w, fb.x, fb.y, fb.z, fb.w};
#pragma unroll
        for (int j = 0; j < 8; j++) {
          unsigned u0 = __float_as_uint(f[j]) & 0xffff0000u;
          float r1 = f[j] - __uint_as_float(u0);
          unsigned u1 = __float_as_uint(r1) & 0xffff0000u;
          float r2 = r1 - __uint_as_float(u1);
          A0[m][j] = (short)(u0 >> 16);
          A1[m][j] = (short)(u1 >> 16);
          A2[m][j] = (short)(__float_as_uint(r2) >> 16);
        }
      }
#pragma unroll
      for (int n = 0; n < 7; n++) {
        int col = (g * 7 + n) * 16 + lr;
        const unsigned short* bp = w3 + (long)col * 224 + k0 + kq * 8;
        short8v B0 = *(const short8v*)(bp);
        short8v B1 = *(const short8v*)(bp + 50176);
        short8v B2 = *(const short8v*)(bp + 100352);
#pragma unroll
        for (int m = 0; m < 4; m++) {
          f32x4 c = acc[m][n];
          c = __builtin_amdgcn_mfma_f32_16x16x32_bf16(A0[m], B0, c, 0, 0, 0);
          c = __builtin_amdgcn_mfma_f32_16x16x32_bf16(A0[m], B1, c, 0, 0, 0);
          c = __builtin_amdgcn_mfma_f32_16x16x32_bf16(A1[m], B0, c, 0, 0, 0);
          c = __builtin_amdgcn_mfma_f32_16x16x32_bf16(A0[m], B2, c, 0, 0, 0);
          c = __builtin_amdgcn_mfma_f32_16x16x32_bf16(A2[m], B0, c, 0, 0, 0);
          c = __builtin_amdgcn_mfma_f32_16x16x32_bf16(A1[m], B1, c, 0, 0, 0);
          c = __builtin_amdgcn_mfma_f32_16x16x32_bf16(A1[m], B2, c, 0, 0, 0);
          c = __builtin_amdgcn_mfma_f32_16x16x32_bf16(A2[m], B1, c, 0, 0, 0);
          acc[m][n] = c;
        }
      }
    }
#pragma unroll
    for (int m = 0; m < 4; m++) {
      long rbase = row0 + wv * 64 + m * 16 + kq * 4;
#pragma unroll
      for (int n = 0; n < 7; n++) {
        int col = (g * 7 + n) * 16 + lr;
        if (col < 200) {
          float bv = bsum[col];
#pragma unroll
          for (int r = 0; r < 4; r++)
            pre[(rbase + r) * 200 + col] = acc[m][n][r] + bv;
        }
      }
    }
  }
}

// ---------------- K2: recurrence via bf16-split MFMA. Block = 16 chains (one M-tile),
// 64 blocks x 4 waves. Per step: S(16x112) = H(16x100)·W^T as 2x2-plane MFMA
// (4 products), acc initialized from prefetched PRE, tanh, h stored to global
// (in-place) + split into bf16 planes in double-buffered LDS (1 barrier/step).
// Layout conventions identical to k_ih (m89-verified).
__global__ __launch_bounds__(256) void k_rnn(
    float* __restrict__ pre, const unsigned short* __restrict__ wh) {
  __shared__ unsigned short Hp[2][2][16][136];  // [buf][plane][row][k], 272B row stride
  int bid = blockIdx.x;
  int dir = bid >> 5;
  int t0 = (bid & 31) * 16;
  int tid = threadIdx.x;
  int wv = tid >> 6, l = tid & 63;
  int lr = l & 15, g = l >> 4;
  int ntiles = (wv < 3) ? 2 : 1;
  int nbase = (wv < 3) ? 2 * wv : 6;
  // B fragments in registers: [n][q] for 2 planes
  short8v B0[2][4], B1[2][4];
#pragma unroll
  for (int n = 0; n < 2; n++) {
    if (n < ntiles) {
      int col = (nbase + n) * 16 + lr;
      const unsigned short* b0p = wh + ((long)(dir * 2 + 0) * 112 + col) * 128 + g * 8;
      const unsigned short* b1p = wh + ((long)(dir * 2 + 1) * 112 + col) * 128 + g * 8;
#pragma unroll
      for (int q = 0; q < 4; q++) {
        B0[n][q] = *(const short8v*)(b0p + q * 32);
        B1[n][q] = *(const short8v*)(b1p + q * 32);
      }
    }
  }
  for (int u = tid; u < 2 * 2 * 16 * 136; u += 256) ((unsigned short*)Hp)[u] = 0;
  long stepoff = dir ? -(long)T_ * 200 : (long)T_ * 200;
  float* base = pre + ((long)(dir ? (B_ - 1) : 0) * T_ + t0) * 200 + dir * 100;
  int goff[2][4];
  bool gok[2][4];
#pragma unroll
  for (int n = 0; n < 2; n++)
#pragma unroll
    for (int r = 0; r < 4; r++) {
      int col = (nbase + n) * 16 + lr;
      int row = g * 4 + r;
      goff[n][r] = row * 200 + col;
      gok[n][r] = (n < ntiles) && (col < 100);
    }
  float pc[2][4];
#pragma unroll
  for (int n = 0; n < 2; n++)
#pragma unroll
    for (int r = 0; r < 4; r++)
      pc[n][r] = gok[n][r] ? base[goff[n][r]] : 0.f;
  __syncthreads();
  int cur = 0;
  float* bp = base;
  for (int s = 0; s < B_; s++) {
    // prefetch next step's PRE (hidden under MFMA)
    float pn[2][4];
#pragma unroll
    for (int n = 0; n < 2; n++)
#pragma unroll
      for (int r = 0; r < 4; r++)
        pn[n][r] = (s < B_ - 1 && gok[n][r]) ? bp[stepoff + goff[n][r]] : 0.f;
    // A fragments: row=lane&15, k=(lane>>4)*8+j, k-tile q*32
    short8v A0[4], A1[4];
#pragma unroll
    for (int q = 0; q < 4; q++) {
      A0[q] = *(const short8v*)&Hp[cur][0][lr][q * 32 + g * 8];
      A1[q] = *(const short8v*)&Hp[cur][1][lr][q * 32 + g * 8];
    }
#pragma unroll
    for (int n = 0; n < 2; n++) {
      if (n < ntiles) {
        f32x4 aca = {pc[n][0], pc[n][1], pc[n][2], pc[n][3]};
        f32x4 acb = {0.f, 0.f, 0.f, 0.f};
#pragma unroll
        for (int q = 0; q < 2; q++) {
          aca = __builtin_amdgcn_mfma_f32_16x16x32_bf16(A0[q], B0[n][q], aca, 0, 0, 0);
          aca = __builtin_amdgcn_mfma_f32_16x16x32_bf16(A0[q], B1[n][q], aca, 0, 0, 0);
          aca = __builtin_amdgcn_mfma_f32_16x16x32_bf16(A1[q], B0[n][q], aca, 0, 0, 0);
          aca = __builtin_amdgcn_mfma_f32_16x16x32_bf16(A1[q], B1[n][q], aca, 0, 0, 0);
        }
#pragma unroll
        for (int q = 2; q < 4; q++) {
          acb = __builtin_amdgcn_mfma_f32_16x16x32_bf16(A0[q], B0[n][q], acb, 0, 0, 0);
          acb = __builtin_amdgcn_mfma_f32_16x16x32_bf16(A0[q], B1[n][q], acb, 0, 0, 0);
          acb = __builtin_amdgcn_mfma_f32_16x16x32_bf16(A1[q], B0[n][q], acb, 0, 0, 0);
          acb = __builtin_amdgcn_mfma_f32_16x16x32_bf16(A1[q], B1[n][q], acb, 0, 0, 0);
        }
        // D: row=(lane>>4)*4+r, col=lane&15 -> tanh, global store, plane split
#pragma unroll
        for (int r = 0; r < 4; r++) {
          float hv = tanhf(aca[r] + acb[r]);
          if (gok[n][r]) bp[goff[n][r]] = hv;
          unsigned u0 = __float_as_uint(hv) & 0xffff0000u;
          float r1 = hv - __uint_as_float(u0);
          unsigned u1 = __float_as_uint(r1) & 0xffff0000u;
          int row = g * 4 + r, col = (nbase + n) * 16 + lr;
          Hp[cur ^ 1][0][row][col] = (unsigned short)(u0 >> 16);
          Hp[cur ^ 1][1][row][col] = (unsigned short)(u1 >> 16);
        }
      }
    }
    __syncthreads();  // all plane writes visible before next step's A reads
    cur ^= 1;
    bp += stepoff;
#pragma unroll
    for (int n = 0; n < 2; n++)
#pragma unroll
      for (int r = 0; r < 4; r++) pc[n][r] = pn[n][r];
  }
}

// ---------------- K3: logits = h @ w_lin^T + b_lin ; softmax over 19. 2 rows/thread.
__global__ __launch_bounds__(256, 4) void k_lin(
    const float* __restrict__ h, const float* __restrict__ wlin,
    const float* __restrict__ blin, float* __restrict__ em) {
  int tid = threadIdx.x;
  long r0 = ((long)blockIdx.x * 256 + tid) * 2;
  const float* h0 = h + r0 * 200;
  float acc0[K_], acc1[K_];
#pragma unroll
  for (int c = 0; c < K_; c++) { float bb = blin[c]; acc0[c] = bb; acc1[c] = bb; }
  for (int kk = 0; kk < 50; kk++) {
    float4 a = *(const float4*)(h0 + 4 * kk);
    float4 b = *(const float4*)(h0 + 200 + 4 * kk);
#pragma unroll
    for (int c = 0; c < K_; c++) {
      float4 wv = *(const float4*)(wlin + c * 200 + 4 * kk);
      acc0[c] += a.x * wv.x + a.y * wv.y + a.z * wv.z + a.w * wv.w;
      acc1[c] += b.x * wv.x + b.y * wv.y + b.z * wv.z + b.w * wv.w;
    }
  }
  float mx0 = acc0[0], mx1 = acc1[0];
#pragma unroll
  for (int c = 1; c < K_; c++) { mx0 = fmaxf(mx0, acc0[c]); mx1 = fmaxf(mx1, acc1[c]); }
  float s0 = 0.f, s1 = 0.f;
#pragma unroll
  for (int c = 0; c < K_; c++) {
    acc0[c] = __expf(acc0[c] - mx0); s0 += acc0[c];
    acc1[c] = __expf(acc1[c] - mx1); s1 += acc1[c];
  }
  float i0 = 1.f / s0, i1 = 1.f / s1;
  float* e0 = em + r0 * K_;
#pragma unroll
  for (int c = 0; c < K_; c++) { e0[c] = acc0[c] * i0; e0[K_ + c] = acc1[c] * i1; }
}

// ---------------- K4: 2 waves per b (round-12 proven, 224 us). LDS ping-pong broadcast.
__global__ __launch_bounds__(128, 1) void k_crf(
    const float* __restrict__ em, const int* __restrict__ y,
    const float* __restrict__ st_g, const float* __restrict__ en_g,
    const float* __restrict__ tr_g,
    float* __restrict__ part, int* __restrict__ cnt,
    float* __restrict__ out) {
  __shared__ __align__(16) float es[T_ * K_];
  __shared__ int ys[T_];
  __shared__ float trs[K_ * K_];
  __shared__ float st[K_], en[K_];
  __shared__ unsigned char hl[511 * K_ + 13];
  __shared__ __align__(16) float zbuf[2][20];
  __shared__ __align__(16) float vbuf[2][20];
  int b = blockIdx.x;
  int tid = threadIdx.x;
  int wv = tid >> 6, lane = tid & 63;
  const float4* eb4 = (const float4*)(em + (long)b * T_ * K_);
  for (int u = tid; u < T_ * K_ / 4; u += 128) ((float4*)es)[u] = eb4[u];
  for (int u = tid; u < T_; u += 128) ys[u] = y[b * T_ + u];
  for (int u = tid; u < K_ * K_; u += 128) trs[u] = tr_g[u];
  if (tid < K_) { st[tid] = st_g[tid]; en[tid] = en_g[tid]; }
  if (tid == 19) { zbuf[0][19] = -1e30f; zbuf[1][19] = -1e30f; vbuf[0][19] = -1e30f; vbuf[1][19] = -1e30f; }
  __syncthreads();
  int lmin = T_;
  for (int u = lane; u < T_; u += 64)
    if (ys[u] == -1 && u < lmin) lmin = u;
#pragma unroll
  for (int off = 32; off; off >>= 1) {
    int o = __shfl_xor(lmin, off, 64);
    lmin = lmin < o ? lmin : o;
  }
  int len = lmin;  // >= 1

  int jj = lane < K_ ? lane : K_ - 1;
  bool act = lane < K_;
  float enr[20];
#pragma unroll
  for (int q = 0; q < 5; q++) {
    float4 e4 = (q < 4) ? *(const float4*)(&en[4 * q])
                        : make_float4(en[16], en[17], en[18], -1e30f);
    enr[4 * q] = e4.x; enr[4 * q + 1] = e4.y; enr[4 * q + 2] = e4.z; enr[4 * q + 3] = e4.w;
  }

  if (wv == 0) {
    float gacc = 0.f;
    for (int t = 1 + lane; t < len; t += 64)
      gacc += trs[ys[t - 1] * K_ + ys[t]] + es[t * K_ + ys[t]];
#pragma unroll
    for (int off = 32; off; off >>= 1) gacc += __shfl_xor(gacc, off, 64);
    int y0 = ys[0], ylast = ys[len - 1];
    float num = st[y0] + es[y0] + gacc + en[ylast];
    float E[K_];
#pragma unroll
    for (int i = 0; i < K_; i++) E[i] = __expf(trs[i * K_ + jj]);
    if (act) zbuf[0][lane] = st[jj] + es[jj];
    asm volatile("s_waitcnt lgkmcnt(0)" ::: "memory");
    for (int t = 1; t < len; t++) {
      int cur = (t - 1) & 1;
      float zr[20];
#pragma unroll
      for (int q = 0; q < 5; q++) {
        float4 z4 = *(const float4*)(&zbuf[cur][4 * q]);
        zr[4 * q] = z4.x; zr[4 * q + 1] = z4.y; zr[4 * q + 2] = z4.z; zr[4 * q + 3] = z4.w;
      }
      float e = es[t * K_ + jj];
      float s = zr[0];
      float a0 = E[0], a1 = 0.f, a2 = 0.f, a3 = 0.f;
#pragma unroll
      for (int i = 1; i < K_; i++) {
        float pz = __expf(zr[i] - s);
        if ((i & 3) == 1)      a1 = fmaf(pz, E[i], a1);
        else if ((i & 3) == 2) a2 = fmaf(pz, E[i], a2);
        else if ((i & 3) == 3) a3 = fmaf(pz, E[i], a3);
        else                   a0 = fmaf(pz, E[i], a0);
      }
      float nz = e + s + __logf((a0 + a1) + (a2 + a3));
      if (act) zbuf[cur ^ 1][lane] = nz;
      asm volatile("s_waitcnt lgkmcnt(0)" ::: "memory");
    }
    {
      int cur = (len - 1) & 1;
      float zr[20];
#pragma unroll
      for (int q = 0; q < 5; q++) {
        float4 z4 = *(const float4*)(&zbuf[cur][4 * q]);
        zr[4 * q] = z4.x; zr[4 * q + 1] = z4.y; zr[4 * q + 2] = z4.z; zr[4 * q + 3] = z4.w;
      }
      float zf[K_];
#pragma unroll
      for (int i = 0; i < K_; i++) zf[i] = zr[i] + enr[i];
      float m2 = zf[0];
#pragma unroll
      for (int i = 1; i < K_; i++) m2 = fmaxf(m2, zf[i]);
      float sm = 0.f;
#pragma unroll
      for (int i = 0; i < K_; i++) sm += __expf(zf[i] - m2);
      if (lane == 0) part[b] = m2 + __logf(sm) - num;
    }
    int old = -1;
    if (lane == 0) { __threadfence(); old = atomicAdd(cnt, 1); }
    old = __shfl(old, 0, 64);
    if (old == B_ - 1) {
      __threadfence();
      float s = 0.f;
      for (int u = lane; u < B_; u += 64) s += part[u];
#pragma unroll
      for (int off = 32; off; off >>= 1) s += __shfl_xor(s, off, 64);
      if (lane == 0) out[0] = s;
    }
  } else {
    float Tt[K_];
#pragma unroll
    for (int i = 0; i < K_; i++) Tt[i] = trs[i * K_ + jj];
    if (act) vbuf[0][lane] = st[jj] + es[jj];
    asm volatile("s_waitcnt lgkmcnt(0)" ::: "memory");
    for (int t = 1; t < len; t++) {
      int cur = (t - 1) & 1;
      float vr[20];
#pragma unroll
      for (int q = 0; q < 5; q++) {
        float4 v4 = *(const float4*)(&vbuf[cur][4 * q]);
        vr[4 * q] = v4.x; vr[4 * q + 1] = v4.y; vr[4 * q + 2] = v4.z; vr[4 * q + 3] = v4.w;
      }
      float e = es[t * K_ + jj];
      float b0 = -1e30f, b1 = -1e30f, b2 = -1e30f, b3 = -1e30f;
      int a0 = 0, a1 = 5, a2 = 10, a3 = 15;
#pragma unroll
      for (int i = 0; i < 5; i++)  { float c = vr[i] + Tt[i]; if (c > b0) { b0 = c; a0 = i; } }
#pragma unroll
      for (int i = 5; i < 10; i++) { float c = vr[i] + Tt[i]; if (c > b1) { b1 = c; a1 = i; } }
#pragma unroll
      for (int i = 10; i < 15; i++){ float c = vr[i] + Tt[i]; if (c > b2) { b2 = c; a2 = i; } }
#pragma unroll
      for (int i = 15; i < 19; i++){ float c = vr[i] + Tt[i]; if (c > b3) { b3 = c; a3 = i; } }
      if (b1 > b0) { b0 = b1; a0 = a1; }
      if (b2 > b0) { b0 = b2; a0 = a2; }
      if (b3 > b0) { b0 = b3; a0 = a3; }
      if (act) {
        hl[(t - 1) * K_ + lane] = (unsigned char)a0;
        vbuf[cur ^ 1][lane] = b0 + e;
      }
      asm volatile("s_waitcnt lgkmcnt(0)" ::: "memory");
    }
    int aa;
    {
      int cur = (len - 1) & 1;
      float vr[20];
#pragma unroll
      for (int q = 0; q < 5; q++) {
        float4 v4 = *(const float4*)(&vbuf[cur][4 * q]);
        vr[4 * q] = v4.x; vr[4 * q + 1] = v4.y; vr[4 * q + 2] = v4.z; vr[4 * q + 3] = v4.w;
      }
      float bb = vr[0] + enr[0]; aa = 0;
#pragma unroll
      for (int i = 1; i < K_; i++) {
        float c = vr[i] + enr[i];
        if (c > bb) { bb = c; aa = i; }
      }
    }
    float* ob = out + 1 + (long)b * T_;
    for (int u = lane; u < T_; u += 64)
      if (u >= len) ob[u] = -1.f;
    int tag = aa;
    if (lane == 0) ob[len - 1] = (float)tag;
    int vc = (act && len >= 2) ? (int)hl[(len - 2) * K_ + lane] : 0;
    for (int ti = len - 2; ti >= 0; ti--) {
      int vn = 0;
      if (ti > 0 && act) vn = (int)hl[(ti - 1) * K_ + lane];
      int ts = __builtin_amdgcn_readfirstlane(tag);
      tag = __builtin_amdgcn_readlane(vc, ts);
      if (lane == 0) ob[ti] = (float)tag;
      vc = vn;
    }
  }
}

extern "C" void kernel_launch(void* const* d_in, const int* in_sizes, int n_in,
                              void* d_out, int out_size, void* d_ws, size_t ws_size,
                              hipStream_t stream) {
  const float* x      = (const float*)d_in[0];
  const int*   y      = (const int*)d_in[1];
  const float* w_ih_f = (const float*)d_in[2];
  const float* w_hh_f = (const float*)d_in[3];
  const float* b_ih_f = (const float*)d_in[4];
  const float* b_hh_f = (const float*)d_in[5];
  const float* w_ih_b = (const float*)d_in[6];
  const float* w_hh_b = (const float*)d_in[7];
  const float* b_ih_b = (const float*)d_in[8];
  const float* b_hh_b = (const float*)d_in[9];
  const float* w_lin  = (const float*)d_in[10];
  const float* b_lin  = (const float*)d_in[11];
  const float* st     = (const float*)d_in[12];
  const float* en     = (const float*)d_in[13];
  const float* trans  = (const float*)d_in[14];

  char* ws = (char*)d_ws;
  const size_t PRE_OFF  = 0;                          // 131072*200*4 = 104857600
  const size_t EM_OFF   = 104857600;                  // 131072*19*4  = 9961472
  const size_t PART_OFF = EM_OFF + 9961472;           // 1024
  const size_t CNT_OFF  = PART_OFF + 1024;            // 4
  const size_t WH_OFF   = PART_OFF + 4096;            // 4*112*128*2 = 114688
  float* PRE  = (float*)(ws + PRE_OFF);
  float* EM   = (float*)(ws + EM_OFF);
  float* PART = (float*)(ws + PART_OFF);
  int*   CNT  = (int*)(ws + CNT_OFF);
  unsigned short* W3 = (unsigned short*)(ws + EM_OFF);  // consumed before k_lin writes EM
  unsigned short* WH = (unsigned short*)(ws + WH_OFF);
  float* out  = (float*)d_out;

  hipMemsetAsync((void*)CNT, 0, sizeof(int), stream);
  k_wprep<<<196, 256, 0, stream>>>(w_ih_f, w_ih_b, W3);
  k_whprep<<<224, 256, 0, stream>>>(w_hh_f, w_hh_b, WH);
  k_ih<<<512, 256, 0, stream>>>(x, W3, b_ih_f, b_hh_f, b_ih_b, b_hh_b, PRE);
  k_rnn<<<64, 256, 0, stream>>>(PRE, WH);
  k_lin<<<256, 256, 0, stream>>>(PRE, w_lin, b_lin, EM);
  k_crf<<<256, 128, 0, stream>>>(EM, y, st, en, trans, PART, CNT, out);
}

// Round 14
// 659.207 us; speedup vs baseline: 1.4201x; 1.4201x over previous
//
#include <hip/hip_runtime.h>
#include <hip/hip_bf16.h>

#define B_ 256
#define T_ 512
#define IN_ 202
#define HID_ 100
#define K_ 19

typedef __attribute__((ext_vector_type(8))) short short8v;
typedef __attribute__((ext_vector_type(4))) float f32x4;

__device__ __forceinline__ float rl_f(float v, int l) {
  return __int_as_float(__builtin_amdgcn_readlane(__float_as_int(v), l));
}

// ---------------- K0: split [wf;wb] (200x202) into 3 exact bf16 planes, padded to 224x224.
__global__ __launch_bounds__(256, 1) void k_wprep(
    const float* __restrict__ wf, const float* __restrict__ wb,
    unsigned short* __restrict__ w3) {
  int idx = blockIdx.x * 256 + threadIdx.x;
  if (idx >= 224 * 224) return;
  int c = idx / 224, k = idx - (idx / 224) * 224;
  float v = 0.f;
  if (k < IN_) {
    if (c < 100) v = wf[c * IN_ + k];
    else if (c < 200) v = wb[(c - 100) * IN_ + k];
  }
  unsigned u0 = __float_as_uint(v) & 0xffff0000u;
  float r1 = v - __uint_as_float(u0);
  unsigned u1 = __float_as_uint(r1) & 0xffff0000u;
  float r2 = r1 - __uint_as_float(u1);
  w3[idx] = (unsigned short)(u0 >> 16);
  w3[50176 + idx] = (unsigned short)(u1 >> 16);
  w3[100352 + idx] = (unsigned short)(__float_as_uint(r2) >> 16);
}

// ---------------- K1: pre = x . [wf;wb]^T + bias via bf16-split MFMA (round-10 proven).
__global__ __launch_bounds__(256, 2) void k_ih(
    const float* __restrict__ x, const unsigned short* __restrict__ w3,
    const float* __restrict__ bif, const float* __restrict__ bhf,
    const float* __restrict__ bib, const float* __restrict__ bhb,
    float* __restrict__ pre) {
  __shared__ float xs[256 * 36];
  __shared__ float bsum[224];
  int tid = threadIdx.x;
  int wv = tid >> 6, l = tid & 63;
  long row0 = (long)blockIdx.x * 256;
  for (int u = tid; u < 224; u += 256) {
    float bv = 0.f;
    if (u < 100) bv = bif[u] + bhf[u];
    else if (u < 200) bv = bib[u - 100] + bhb[u - 100];
    bsum[u] = bv;
  }
  int lr = l & 15;
  int kq = l >> 4;
  for (int g = 0; g < 2; g++) {
    f32x4 acc[4][7];
#pragma unroll
    for (int m = 0; m < 4; m++)
#pragma unroll
      for (int n = 0; n < 7; n++) acc[m][n] = (f32x4){0.f, 0.f, 0.f, 0.f};
    for (int ck = 0; ck < 7; ck++) {
      int k0 = ck * 32;
      __syncthreads();
#pragma unroll
      for (int i = 0; i < 16; i++) {
        int u = tid + i * 256;
        int r = u >> 4, kp = u & 15;
        int gk = k0 + 2 * kp;
        float2 v = make_float2(0.f, 0.f);
        if (gk < IN_) v = *(const float2*)(x + (row0 + r) * IN_ + gk);
        *(float2*)(&xs[r * 36 + 2 * kp]) = v;
      }
      __syncthreads();
      short8v A0[4], A1[4], A2[4];
#pragma unroll
      for (int m = 0; m < 4; m++) {
        const float* ap = &xs[(wv * 64 + m * 16 + lr) * 36 + kq * 8];
        float4 fa = *(const float4*)(ap);
        float4 fb = *(const float4*)(ap + 4);
        float f[8] = {fa.x, fa.y, fa.z, fa.w, fb.x, fb.y, fb.z, fb.w};
#pragma unroll
        for (int j = 0; j < 8; j++) {
          unsigned u0 = __float_as_uint(f[j]) & 0xffff0000u;
          float r1 = f[j] - __uint_as_float(u0);
          unsigned u1 = __float_as_uint(r1) & 0xffff0000u;
          float r2 = r1 - __uint_as_float(u1);
          A0[m][j] = (short)(u0 >> 16);
          A1[m][j] = (short)(u1 >> 16);
          A2[m][j] = (short)(__float_as_uint(r2) >> 16);
        }
      }
#pragma unroll
      for (int n = 0; n < 7; n++) {
        int col = (g * 7 + n) * 16 + lr;
        const unsigned short* bp = w3 + (long)col * 224 + k0 + kq * 8;
        short8v B0 = *(const short8v*)(bp);
        short8v B1 = *(const short8v*)(bp + 50176);
        short8v B2 = *(const short8v*)(bp + 100352);
#pragma unroll
        for (int m = 0; m < 4; m++) {
          f32x4 c = acc[m][n];
          c = __builtin_amdgcn_mfma_f32_16x16x32_bf16(A0[m], B0, c, 0, 0, 0);
          c = __builtin_amdgcn_mfma_f32_16x16x32_bf16(A0[m], B1, c, 0, 0, 0);
          c = __builtin_amdgcn_mfma_f32_16x16x32_bf16(A1[m], B0, c, 0, 0, 0);
          c = __builtin_amdgcn_mfma_f32_16x16x32_bf16(A0[m], B2, c, 0, 0, 0);
          c = __builtin_amdgcn_mfma_f32_16x16x32_bf16(A2[m], B0, c, 0, 0, 0);
          c = __builtin_amdgcn_mfma_f32_16x16x32_bf16(A1[m], B1, c, 0, 0, 0);
          c = __builtin_amdgcn_mfma_f32_16x16x32_bf16(A1[m], B2, c, 0, 0, 0);
          c = __builtin_amdgcn_mfma_f32_16x16x32_bf16(A2[m], B1, c, 0, 0, 0);
          acc[m][n] = c;
        }
      }
    }
#pragma unroll
    for (int m = 0; m < 4; m++) {
      long rbase = row0 + wv * 64 + m * 16 + kq * 4;
#pragma unroll
      for (int n = 0; n < 7; n++) {
        int col = (g * 7 + n) * 16 + lr;
        if (col < 200) {
          float bv = bsum[col];
#pragma unroll
          for (int r = 0; r < 4; r++)
            pre[(rbase + r) * 200 + col] = acc[m][n][r] + bv;
        }
      }
    }
  }
}

// ---------------- K2: recurrence over b (256 steps); 4 waves per (t,dir) chain
// (round-5 proven, 237 us). MFMA variant (round 13) regressed: 16 chains/block
// -> only 64 blocks -> 192 CUs idle. Serial recurrences want MANY waves.
template <int KO, int KN, bool OW>
__device__ __forceinline__ void rnn_loop(
    float* __restrict__ p, long step, int row, bool owns,
    const float* __restrict__ w, float (*hb)[104], float* __restrict__ ps) {
  float wr[KN];
#pragma unroll
  for (int i = 0; i < KN / 4; i++) {
    float4 w4 = *(const float4*)(w + row * HID_ + KO + 4 * i);
    wr[4 * i + 0] = w4.x; wr[4 * i + 1] = w4.y;
    wr[4 * i + 2] = w4.z; wr[4 * i + 3] = w4.w;
  }
  float a = 0.f;
  if (OW) a = p[row];
  for (int s = 0; s < B_; s++) {
    int cur = s & 1;
    float a_next = 0.f;
    if (OW && s < B_ - 1) a_next = p[step + row];
    float ac0 = OW ? a : 0.f, ac1 = 0.f, ac2 = 0.f, ac3 = 0.f;
#pragma unroll
    for (int i = 0; i < KN / 4; i++) {
      float4 h4 = *(const float4*)(&hb[cur][KO + 4 * i]);
      ac0 = fmaf(h4.x, wr[4 * i + 0], ac0);
      ac1 = fmaf(h4.y, wr[4 * i + 1], ac1);
      ac2 = fmaf(h4.z, wr[4 * i + 2], ac2);
      ac3 = fmaf(h4.w, wr[4 * i + 3], ac3);
    }
    float partial = (ac0 + ac1) + (ac2 + ac3);
    if (!OW && owns) ps[row] = partial;
    __syncthreads();
    if (OW) {
      float hnew = tanhf(partial + ps[row]);
      if (owns) {
        hb[cur ^ 1][row] = hnew;
        p[row] = hnew;
      }
    }
    p += step;
    a = a_next;
    __syncthreads();
  }
}

__global__ __launch_bounds__(256, 4) void k_rnn(
    float* __restrict__ pre,
    const float* __restrict__ whf, const float* __restrict__ whb) {
  __shared__ float hb[2][104];
  __shared__ float ps[104];
  int bid = blockIdx.x;
  int dir = bid >> 9;
  int t = bid & 511;
  const float* w = dir ? whb : whf;
  int tid = threadIdx.x;
  int wv = tid >> 6, lane = tid & 63;
  int grp = wv >> 1;
  int khalf = wv & 1;
  int row = grp ? (64 + (lane < 36 ? lane : 35)) : lane;
  bool owns = grp ? (lane < 36) : true;
  long step = dir ? -(long)(T_ * 200) : (long)(T_ * 200);
  float* p = pre + ((long)(dir ? (B_ - 1) : 0) * T_ + t) * 200 + dir * 100;
  if (tid < 104) hb[0][tid] = 0.f;
  __syncthreads();
  if (khalf == 0) rnn_loop<0, 52, true >(p, step, row, owns, w, hb, ps);
  else            rnn_loop<52, 48, false>(p, step, row, owns, w, hb, ps);
}

// ---------------- K3: logits = h @ w_lin^T + b_lin ; softmax over 19. 2 rows/thread.
__global__ __launch_bounds__(256, 4) void k_lin(
    const float* __restrict__ h, const float* __restrict__ wlin,
    const float* __restrict__ blin, float* __restrict__ em) {
  int tid = threadIdx.x;
  long r0 = ((long)blockIdx.x * 256 + tid) * 2;
  const float* h0 = h + r0 * 200;
  float acc0[K_], acc1[K_];
#pragma unroll
  for (int c = 0; c < K_; c++) { float bb = blin[c]; acc0[c] = bb; acc1[c] = bb; }
  for (int kk = 0; kk < 50; kk++) {
    float4 a = *(const float4*)(h0 + 4 * kk);
    float4 b = *(const float4*)(h0 + 200 + 4 * kk);
#pragma unroll
    for (int c = 0; c < K_; c++) {
      float4 wv = *(const float4*)(wlin + c * 200 + 4 * kk);
      acc0[c] += a.x * wv.x + a.y * wv.y + a.z * wv.z + a.w * wv.w;
      acc1[c] += b.x * wv.x + b.y * wv.y + b.z * wv.z + b.w * wv.w;
    }
  }
  float mx0 = acc0[0], mx1 = acc1[0];
#pragma unroll
  for (int c = 1; c < K_; c++) { mx0 = fmaxf(mx0, acc0[c]); mx1 = fmaxf(mx1, acc1[c]); }
  float s0 = 0.f, s1 = 0.f;
#pragma unroll
  for (int c = 0; c < K_; c++) {
    acc0[c] = __expf(acc0[c] - mx0); s0 += acc0[c];
    acc1[c] = __expf(acc1[c] - mx1); s1 += acc1[c];
  }
  float i0 = 1.f / s0, i1 = 1.f / s1;
  float* e0 = em + r0 * K_;
#pragma unroll
  for (int c = 0; c < K_; c++) { e0[c] = acc0[c] * i0; e0[K_ + c] = acc1[c] * i1; }
}

// ---------------- K4: 2 waves per b. wave0 logZ in SCALED PROBABILITY SPACE:
// P' = (E^T P) * exp(e) with exact power-of-2 renormalization (exponent bits of
// P[0]; integer kacc, one log at the end). No transcendentals on the serial
// chain (exp(e_next) computed off-chain on prefetched value). wave1 Viterbi
// (round-12 proven, labels bit-identical). LDS ping-pong broadcast for states.
__global__ __launch_bounds__(128, 1) void k_crf(
    const float* __restrict__ em, const int* __restrict__ y,
    const float* __restrict__ st_g, const float* __restrict__ en_g,
    const float* __restrict__ tr_g,
    float* __restrict__ part, int* __restrict__ cnt,
    float* __restrict__ out) {
  __shared__ __align__(16) float es[T_ * K_];
  __shared__ int ys[T_];
  __shared__ float trs[K_ * K_];
  __shared__ float st[K_], en[K_];
  __shared__ unsigned char hl[511 * K_ + 13];
  __shared__ __align__(16) float zbuf[2][20];
  __shared__ __align__(16) float vbuf[2][20];
  int b = blockIdx.x;
  int tid = threadIdx.x;
  int wv = tid >> 6, lane = tid & 63;
  const float4* eb4 = (const float4*)(em + (long)b * T_ * K_);
  for (int u = tid; u < T_ * K_ / 4; u += 128) ((float4*)es)[u] = eb4[u];
  for (int u = tid; u < T_; u += 128) ys[u] = y[b * T_ + u];
  for (int u = tid; u < K_ * K_; u += 128) trs[u] = tr_g[u];
  if (tid < K_) { st[tid] = st_g[tid]; en[tid] = en_g[tid]; }
  if (tid == 19) { zbuf[0][19] = 0.f; zbuf[1][19] = 0.f; vbuf[0][19] = -1e30f; vbuf[1][19] = -1e30f; }
  __syncthreads();
  int lmin = T_;
  for (int u = lane; u < T_; u += 64)
    if (ys[u] == -1 && u < lmin) lmin = u;
#pragma unroll
  for (int off = 32; off; off >>= 1) {
    int o = __shfl_xor(lmin, off, 64);
    lmin = lmin < o ? lmin : o;
  }
  int len = lmin;  // >= 1

  int jj = lane < K_ ? lane : K_ - 1;
  bool act = lane < K_;
  float enr[20];
#pragma unroll
  for (int q = 0; q < 5; q++) {
    float4 e4 = (q < 4) ? *(const float4*)(&en[4 * q])
                        : make_float4(en[16], en[17], en[18], -1e30f);
    enr[4 * q] = e4.x; enr[4 * q + 1] = e4.y; enr[4 * q + 2] = e4.z; enr[4 * q + 3] = e4.w;
  }

  if (wv == 0) {
    // ---- gold-path score: parallel gather (log space, unchanged)
    float gacc = 0.f;
    for (int t = 1 + lane; t < len; t += 64)
      gacc += trs[ys[t - 1] * K_ + ys[t]] + es[t * K_ + ys[t]];
#pragma unroll
    for (int off = 32; off; off >>= 1) gacc += __shfl_xor(gacc, off, 64);
    int y0 = ys[0], ylast = ys[len - 1];
    float num = st[y0] + es[y0] + gacc + en[ylast];
    // ---- serial forward, scaled probability space
    float Ecol[K_];
#pragma unroll
    for (int i = 0; i < K_; i++) Ecol[i] = __expf(trs[i * K_ + jj]);
    if (act) zbuf[0][lane] = __expf(st[jj] + es[jj]);  // P0
    asm volatile("s_waitcnt lgkmcnt(0)" ::: "memory");
    int kacc = 0;
    float ee = __expf(es[K_ + jj]);  // exp(e) for t=1
    for (int t = 1; t < len; t++) {
      int cur = (t - 1) & 1;
      float pr[20];
#pragma unroll
      for (int q = 0; q < 5; q++) {
        float4 z4 = *(const float4*)(&zbuf[cur][4 * q]);  // uniform -> broadcast
        pr[4 * q] = z4.x; pr[4 * q + 1] = z4.y; pr[4 * q + 2] = z4.z; pr[4 * q + 3] = z4.w;
      }
      int tn = (t + 1 < T_) ? t + 1 : T_ - 1;
      float e_next = es[tn * K_ + jj];     // prefetch (off chain)
      // exact power-of-2 renorm from P[0]'s exponent
      unsigned pb = __float_as_uint(pr[0]);
      int ex = (int)((pb >> 23) & 0xff);
      float scale = __uint_as_float((unsigned)(254 - ex) << 23);
      kacc += ex - 127;
      float a0 = 0.f, a1 = 0.f, a2 = 0.f, a3 = 0.f;
#pragma unroll
      for (int i = 0; i < K_; i++) {
        if ((i & 3) == 0)      a0 = fmaf(pr[i], Ecol[i], a0);
        else if ((i & 3) == 1) a1 = fmaf(pr[i], Ecol[i], a1);
        else if ((i & 3) == 2) a2 = fmaf(pr[i], Ecol[i], a2);
        else                   a3 = fmaf(pr[i], Ecol[i], a3);
      }
      float nz = (((a0 + a1) + (a2 + a3)) * ee) * scale;
      if (act) zbuf[cur ^ 1][lane] = nz;
      asm volatile("s_waitcnt lgkmcnt(0)" ::: "memory");
      ee = __expf(e_next);  // off-chain: for step t+1
    }
    // final: logZ = log(sum P[i]*exp(en[i])) + kacc*ln2
    {
      int cur = (len - 1) & 1;
      float pr[20];
#pragma unroll
      for (int q = 0; q < 5; q++) {
        float4 z4 = *(const float4*)(&zbuf[cur][4 * q]);
        pr[4 * q] = z4.x; pr[4 * q + 1] = z4.y; pr[4 * q + 2] = z4.z; pr[4 * q + 3] = z4.w;
      }
      float sm = 0.f;
#pragma unroll
      for (int i = 0; i < K_; i++) sm += pr[i] * __expf(enr[i]);
      if (lane == 0) part[b] = __logf(sm) + (float)kacc * 0.6931471805599453f - num;
    }
    int old = -1;
    if (lane == 0) { __threadfence(); old = atomicAdd(cnt, 1); }
    old = __shfl(old, 0, 64);
    if (old == B_ - 1) {
      __threadfence();
      float s = 0.f;
      for (int u = lane; u < B_; u += 64) s += part[u];
#pragma unroll
      for (int off = 32; off; off >>= 1) s += __shfl_xor(s, off, 64);
      if (lane == 0) out[0] = s;
    }
  } else {
    float Tt[K_];
#pragma unroll
    for (int i = 0; i < K_; i++) Tt[i] = trs[i * K_ + jj];
    if (act) vbuf[0][lane] = st[jj] + es[jj];
    asm volatile("s_waitcnt lgkmcnt(0)" ::: "memory");
    for (int t = 1; t < len; t++) {
      int cur = (t - 1) & 1;
      float vr[20];
#pragma unroll
      for (int q = 0; q < 5; q++) {
        float4 v4 = *(const float4*)(&vbuf[cur][4 * q]);
        vr[4 * q] = v4.x; vr[4 * q + 1] = v4.y; vr[4 * q + 2] = v4.z; vr[4 * q + 3] = v4.w;
      }
      float e = es[t * K_ + jj];
      float b0 = -1e30f, b1 = -1e30f, b2 = -1e30f, b3 = -1e30f;
      int a0 = 0, a1 = 5, a2 = 10, a3 = 15;
#pragma unroll
      for (int i = 0; i < 5; i++)  { float c = vr[i] + Tt[i]; if (c > b0) { b0 = c; a0 = i; } }
#pragma unroll
      for (int i = 5; i < 10; i++) { float c = vr[i] + Tt[i]; if (c > b1) { b1 = c; a1 = i; } }
#pragma unroll
      for (int i = 10; i < 15; i++){ float c = vr[i] + Tt[i]; if (c > b2) { b2 = c; a2 = i; } }
#pragma unroll
      for (int i = 15; i < 19; i++){ float c = vr[i] + Tt[i]; if (c > b3) { b3 = c; a3 = i; } }
      if (b1 > b0) { b0 = b1; a0 = a1; }
      if (b2 > b0) { b0 = b2; a0 = a2; }
      if (b3 > b0) { b0 = b3; a0 = a3; }
      if (act) {
        hl[(t - 1) * K_ + lane] = (unsigned char)a0;
        vbuf[cur ^ 1][lane] = b0 + e;
      }
      asm volatile("s_waitcnt lgkmcnt(0)" ::: "memory");
    }
    int aa;
    {
      int cur = (len - 1) & 1;
      float vr[20];
#pragma unroll
      for (int q = 0; q < 5; q++) {
        float4 v4 = *(const float4*)(&vbuf[cur][4 * q]);
        vr[4 * q] = v4.x; vr[4 * q + 1] = v4.y; vr[4 * q + 2] = v4.z; vr[4 * q + 3] = v4.w;
      }
      float bb = vr[0] + enr[0]; aa = 0;
#pragma unroll
      for (int i = 1; i < K_; i++) {
        float c = vr[i] + enr[i];
        if (c > bb) { bb = c; aa = i; }
      }
    }
    float* ob = out + 1 + (long)b * T_;
    for (int u = lane; u < T_; u += 64)
      if (u >= len) ob[u] = -1.f;
    int tag = aa;
    if (lane == 0) ob[len - 1] = (float)tag;
    int vc = (act && len >= 2) ? (int)hl[(len - 2) * K_ + lane] : 0;
    for (int ti = len - 2; ti >= 0; ti--) {
      int vn = 0;
      if (ti > 0 && act) vn = (int)hl[(ti - 1) * K_ + lane];
      int ts = __builtin_amdgcn_readfirstlane(tag);
      tag = __builtin_amdgcn_readlane(vc, ts);
      if (lane == 0) ob[ti] = (float)tag;
      vc = vn;
    }
  }
}

extern "C" void kernel_launch(void* const* d_in, const int* in_sizes, int n_in,
                              void* d_out, int out_size, void* d_ws, size_t ws_size,
                              hipStream_t stream) {
  const float* x      = (const float*)d_in[0];
  const int*   y      = (const int*)d_in[1];
  const float* w_ih_f = (const float*)d_in[2];
  const float* w_hh_f = (const float*)d_in[3];
  const float* b_ih_f = (const float*)d_in[4];
  const float* b_hh_f = (const float*)d_in[5];
  const float* w_ih_b = (const float*)d_in[6];
  const float* w_hh_b = (const float*)d_in[7];
  const float* b_ih_b = (const float*)d_in[8];
  const float* b_hh_b = (const float*)d_in[9];
  const float* w_lin  = (const float*)d_in[10];
  const float* b_lin  = (const float*)d_in[11];
  const float* st     = (const float*)d_in[12];
  const float* en     = (const float*)d_in[13];
  const float* trans  = (const float*)d_in[14];

  char* ws = (char*)d_ws;
  const size_t PRE_OFF  = 0;                          // 131072*200*4 = 104857600
  const size_t EM_OFF   = 104857600;                  // 131072*19*4  = 9961472
  const size_t PART_OFF = EM_OFF + 9961472;           // 1024
  const size_t CNT_OFF  = PART_OFF + 1024;            // 4
  float* PRE  = (float*)(ws + PRE_OFF);
  float* EM   = (float*)(ws + EM_OFF);
  float* PART = (float*)(ws + PART_OFF);
  int*   CNT  = (int*)(ws + CNT_OFF);
  unsigned short* W3 = (unsigned short*)(ws + EM_OFF);  // consumed before k_lin writes EM
  float* out  = (float*)d_out;

  hipMemsetAsync((void*)CNT, 0, sizeof(int), stream);
  k_wprep<<<196, 256, 0, stream>>>(w_ih_f, w_ih_b, W3);
  k_ih<<<512, 256, 0, stream>>>(x, W3, b_ih_f, b_hh_f, b_ih_b, b_hh_b, PRE);
  k_rnn<<<1024, 256, 0, stream>>>(PRE, w_hh_f, w_hh_b);
  k_lin<<<256, 256, 0, stream>>>(PRE, w_lin, b_lin, EM);
  k_crf<<<256, 128, 0, stream>>>(EM, y, st, en, trans, PART, CNT, out);
}

// Round 15
// 631.961 us; speedup vs baseline: 1.4813x; 1.0431x over previous
//
#include <hip/hip_runtime.h>
#include <hip/hip_bf16.h>

#define B_ 256
#define T_ 512
#define IN_ 202
#define HID_ 100
#define K_ 19

typedef __attribute__((ext_vector_type(8))) short short8v;
typedef __attribute__((ext_vector_type(4))) float f32x4;

__device__ __forceinline__ float rl_f(float v, int l) {
  return __int_as_float(__builtin_amdgcn_readlane(__float_as_int(v), l));
}
// register->register broadcast of lane l via LDS crossbar (no storage, no SGPR hazard)
__device__ __forceinline__ float bcast_f(float v, int l) {
  return __int_as_float(__builtin_amdgcn_ds_bpermute(l * 4, __float_as_int(v)));
}

// ---------------- K0: split [wf;wb] (200x202) into 3 exact bf16 planes, padded to 224x224.
__global__ __launch_bounds__(256, 1) void k_wprep(
    const float* __restrict__ wf, const float* __restrict__ wb,
    unsigned short* __restrict__ w3) {
  int idx = blockIdx.x * 256 + threadIdx.x;
  if (idx >= 224 * 224) return;
  int c = idx / 224, k = idx - (idx / 224) * 224;
  float v = 0.f;
  if (k < IN_) {
    if (c < 100) v = wf[c * IN_ + k];
    else if (c < 200) v = wb[(c - 100) * IN_ + k];
  }
  unsigned u0 = __float_as_uint(v) & 0xffff0000u;
  float r1 = v - __uint_as_float(u0);
  unsigned u1 = __float_as_uint(r1) & 0xffff0000u;
  float r2 = r1 - __uint_as_float(u1);
  w3[idx] = (unsigned short)(u0 >> 16);
  w3[50176 + idx] = (unsigned short)(u1 >> 16);
  w3[100352 + idx] = (unsigned short)(__float_as_uint(r2) >> 16);
}

// ---------------- K1: pre = x . [wf;wb]^T + bias via bf16-split MFMA (round-10 proven).
__global__ __launch_bounds__(256, 2) void k_ih(
    const float* __restrict__ x, const unsigned short* __restrict__ w3,
    const float* __restrict__ bif, const float* __restrict__ bhf,
    const float* __restrict__ bib, const float* __restrict__ bhb,
    float* __restrict__ pre) {
  __shared__ float xs[256 * 36];
  __shared__ float bsum[224];
  int tid = threadIdx.x;
  int wv = tid >> 6, l = tid & 63;
  long row0 = (long)blockIdx.x * 256;
  for (int u = tid; u < 224; u += 256) {
    float bv = 0.f;
    if (u < 100) bv = bif[u] + bhf[u];
    else if (u < 200) bv = bib[u - 100] + bhb[u - 100];
    bsum[u] = bv;
  }
  int lr = l & 15;
  int kq = l >> 4;
  for (int g = 0; g < 2; g++) {
    f32x4 acc[4][7];
#pragma unroll
    for (int m = 0; m < 4; m++)
#pragma unroll
      for (int n = 0; n < 7; n++) acc[m][n] = (f32x4){0.f, 0.f, 0.f, 0.f};
    for (int ck = 0; ck < 7; ck++) {
      int k0 = ck * 32;
      __syncthreads();
#pragma unroll
      for (int i = 0; i < 16; i++) {
        int u = tid + i * 256;
        int r = u >> 4, kp = u & 15;
        int gk = k0 + 2 * kp;
        float2 v = make_float2(0.f, 0.f);
        if (gk < IN_) v = *(const float2*)(x + (row0 + r) * IN_ + gk);
        *(float2*)(&xs[r * 36 + 2 * kp]) = v;
      }
      __syncthreads();
      short8v A0[4], A1[4], A2[4];
#pragma unroll
      for (int m = 0; m < 4; m++) {
        const float* ap = &xs[(wv * 64 + m * 16 + lr) * 36 + kq * 8];
        float4 fa = *(const float4*)(ap);
        float4 fb = *(const float4*)(ap + 4);
        float f[8] = {fa.x, fa.y, fa.z, fa.w, fb.x, fb.y, fb.z, fb.w};
#pragma unroll
        for (int j = 0; j < 8; j++) {
          unsigned u0 = __float_as_uint(f[j]) & 0xffff0000u;
          float r1 = f[j] - __uint_as_float(u0);
          unsigned u1 = __float_as_uint(r1) & 0xffff0000u;
          float r2 = r1 - __uint_as_float(u1);
          A0[m][j] = (short)(u0 >> 16);
          A1[m][j] = (short)(u1 >> 16);
          A2[m][j] = (short)(__float_as_uint(r2) >> 16);
        }
      }
#pragma unroll
      for (int n = 0; n < 7; n++) {
        int col = (g * 7 + n) * 16 + lr;
        const unsigned short* bp = w3 + (long)col * 224 + k0 + kq * 8;
        short8v B0 = *(const short8v*)(bp);
        short8v B1 = *(const short8v*)(bp + 50176);
        short8v B2 = *(const short8v*)(bp + 100352);
#pragma unroll
        for (int m = 0; m < 4; m++) {
          f32x4 c = acc[m][n];
          c = __builtin_amdgcn_mfma_f32_16x16x32_bf16(A0[m], B0, c, 0, 0, 0);
          c = __builtin_amdgcn_mfma_f32_16x16x32_bf16(A0[m], B1, c, 0, 0, 0);
          c = __builtin_amdgcn_mfma_f32_16x16x32_bf16(A1[m], B0, c, 0, 0, 0);
          c = __builtin_amdgcn_mfma_f32_16x16x32_bf16(A0[m], B2, c, 0, 0, 0);
          c = __builtin_amdgcn_mfma_f32_16x16x32_bf16(A2[m], B0, c, 0, 0, 0);
          c = __builtin_amdgcn_mfma_f32_16x16x32_bf16(A1[m], B1, c, 0, 0, 0);
          c = __builtin_amdgcn_mfma_f32_16x16x32_bf16(A1[m], B2, c, 0, 0, 0);
          c = __builtin_amdgcn_mfma_f32_16x16x32_bf16(A2[m], B1, c, 0, 0, 0);
          acc[m][n] = c;
        }
      }
    }
#pragma unroll
    for (int m = 0; m < 4; m++) {
      long rbase = row0 + wv * 64 + m * 16 + kq * 4;
#pragma unroll
      for (int n = 0; n < 7; n++) {
        int col = (g * 7 + n) * 16 + lr;
        if (col < 200) {
          float bv = bsum[col];
#pragma unroll
          for (int r = 0; r < 4; r++)
            pre[(rbase + r) * 200 + col] = acc[m][n][r] + bv;
        }
      }
    }
  }
}

// ---------------- K2: recurrence over b (256 steps); 4 waves per (t,dir) chain (round-5 proven).
template <int KO, int KN, bool OW>
__device__ __forceinline__ void rnn_loop(
    float* __restrict__ p, long step, int row, bool owns,
    const float* __restrict__ w, float (*hb)[104], float* __restrict__ ps) {
  float wr[KN];
#pragma unroll
  for (int i = 0; i < KN / 4; i++) {
    float4 w4 = *(const float4*)(w + row * HID_ + KO + 4 * i);
    wr[4 * i + 0] = w4.x; wr[4 * i + 1] = w4.y;
    wr[4 * i + 2] = w4.z; wr[4 * i + 3] = w4.w;
  }
  float a = 0.f;
  if (OW) a = p[row];
  for (int s = 0; s < B_; s++) {
    int cur = s & 1;
    float a_next = 0.f;
    if (OW && s < B_ - 1) a_next = p[step + row];
    float ac0 = OW ? a : 0.f, ac1 = 0.f, ac2 = 0.f, ac3 = 0.f;
#pragma unroll
    for (int i = 0; i < KN / 4; i++) {
      float4 h4 = *(const float4*)(&hb[cur][KO + 4 * i]);
      ac0 = fmaf(h4.x, wr[4 * i + 0], ac0);
      ac1 = fmaf(h4.y, wr[4 * i + 1], ac1);
      ac2 = fmaf(h4.z, wr[4 * i + 2], ac2);
      ac3 = fmaf(h4.w, wr[4 * i + 3], ac3);
    }
    float partial = (ac0 + ac1) + (ac2 + ac3);
    if (!OW && owns) ps[row] = partial;
    __syncthreads();
    if (OW) {
      float hnew = tanhf(partial + ps[row]);
      if (owns) {
        hb[cur ^ 1][row] = hnew;
        p[row] = hnew;
      }
    }
    p += step;
    a = a_next;
    __syncthreads();
  }
}

__global__ __launch_bounds__(256, 4) void k_rnn(
    float* __restrict__ pre,
    const float* __restrict__ whf, const float* __restrict__ whb) {
  __shared__ float hb[2][104];
  __shared__ float ps[104];
  int bid = blockIdx.x;
  int dir = bid >> 9;
  int t = bid & 511;
  const float* w = dir ? whb : whf;
  int tid = threadIdx.x;
  int wv = tid >> 6, lane = tid & 63;
  int grp = wv >> 1;
  int khalf = wv & 1;
  int row = grp ? (64 + (lane < 36 ? lane : 35)) : lane;
  bool owns = grp ? (lane < 36) : true;
  long step = dir ? -(long)(T_ * 200) : (long)(T_ * 200);
  float* p = pre + ((long)(dir ? (B_ - 1) : 0) * T_ + t) * 200 + dir * 100;
  if (tid < 104) hb[0][tid] = 0.f;
  __syncthreads();
  if (khalf == 0) rnn_loop<0, 52, true >(p, step, row, owns, w, hb, ps);
  else            rnn_loop<52, 48, false>(p, step, row, owns, w, hb, ps);
}

// ---------------- K3: logits = h @ w_lin^T + b_lin ; softmax over 19. 2 rows/thread.
__global__ __launch_bounds__(256, 4) void k_lin(
    const float* __restrict__ h, const float* __restrict__ wlin,
    const float* __restrict__ blin, float* __restrict__ em) {
  int tid = threadIdx.x;
  long r0 = ((long)blockIdx.x * 256 + tid) * 2;
  const float* h0 = h + r0 * 200;
  float acc0[K_], acc1[K_];
#pragma unroll
  for (int c = 0; c < K_; c++) { float bb = blin[c]; acc0[c] = bb; acc1[c] = bb; }
  for (int kk = 0; kk < 50; kk++) {
    float4 a = *(const float4*)(h0 + 4 * kk);
    float4 b = *(const float4*)(h0 + 200 + 4 * kk);
#pragma unroll
    for (int c = 0; c < K_; c++) {
      float4 wv = *(const float4*)(wlin + c * 200 + 4 * kk);
      acc0[c] += a.x * wv.x + a.y * wv.y + a.z * wv.z + a.w * wv.w;
      acc1[c] += b.x * wv.x + b.y * wv.y + b.z * wv.z + b.w * wv.w;
    }
  }
  float mx0 = acc0[0], mx1 = acc1[0];
#pragma unroll
  for (int c = 1; c < K_; c++) { mx0 = fmaxf(mx0, acc0[c]); mx1 = fmaxf(mx1, acc1[c]); }
  float s0 = 0.f, s1 = 0.f;
#pragma unroll
  for (int c = 0; c < K_; c++) {
    acc0[c] = __expf(acc0[c] - mx0); s0 += acc0[c];
    acc1[c] = __expf(acc1[c] - mx1); s1 += acc1[c];
  }
  float i0 = 1.f / s0, i1 = 1.f / s1;
  float* e0 = em + r0 * K_;
#pragma unroll
  for (int c = 0; c < K_; c++) { e0[c] = acc0[c] * i0; e0[K_ + c] = acc1[c] * i1; }
}

// ---------------- K4: 2 waves per b. State broadcast via ds_bpermute (reg->reg,
// no LDS ping-pong round trip on the serial chain). wave0: logZ in scaled
// probability space (round-14 proven math) + parallel gold-path gather.
// wave1: Viterbi forward + backtrack (identical semantics to round-12 labels).
__global__ __launch_bounds__(128, 1) void k_crf(
    const float* __restrict__ em, const int* __restrict__ y,
    const float* __restrict__ st_g, const float* __restrict__ en_g,
    const float* __restrict__ tr_g,
    float* __restrict__ part, int* __restrict__ cnt,
    float* __restrict__ out) {
  __shared__ __align__(16) float es[T_ * K_];
  __shared__ int ys[T_];
  __shared__ float trs[K_ * K_];
  __shared__ float st[K_], en[K_];
  __shared__ unsigned char hl[511 * K_ + 13];
  int b = blockIdx.x;
  int tid = threadIdx.x;
  int wv = tid >> 6, lane = tid & 63;
  const float4* eb4 = (const float4*)(em + (long)b * T_ * K_);
  for (int u = tid; u < T_ * K_ / 4; u += 128) ((float4*)es)[u] = eb4[u];
  for (int u = tid; u < T_; u += 128) ys[u] = y[b * T_ + u];
  for (int u = tid; u < K_ * K_; u += 128) trs[u] = tr_g[u];
  if (tid < K_) { st[tid] = st_g[tid]; en[tid] = en_g[tid]; }
  __syncthreads();
  int lmin = T_;
  for (int u = lane; u < T_; u += 64)
    if (ys[u] == -1 && u < lmin) lmin = u;
#pragma unroll
  for (int off = 32; off; off >>= 1) {
    int o = __shfl_xor(lmin, off, 64);
    lmin = lmin < o ? lmin : o;
  }
  int len = lmin;  // >= 1

  int jj = lane < K_ ? lane : K_ - 1;
  bool act = lane < K_;
  float enr[20];
#pragma unroll
  for (int q = 0; q < 5; q++) {
    float4 e4 = (q < 4) ? *(const float4*)(&en[4 * q])
                        : make_float4(en[16], en[17], en[18], -1e30f);
    enr[4 * q] = e4.x; enr[4 * q + 1] = e4.y; enr[4 * q + 2] = e4.z; enr[4 * q + 3] = e4.w;
  }

  if (wv == 0) {
    // ---- gold-path score: parallel gather (log space)
    float gacc = 0.f;
    for (int t = 1 + lane; t < len; t += 64)
      gacc += trs[ys[t - 1] * K_ + ys[t]] + es[t * K_ + ys[t]];
#pragma unroll
    for (int off = 32; off; off >>= 1) gacc += __shfl_xor(gacc, off, 64);
    int y0 = ys[0], ylast = ys[len - 1];
    float num = st[y0] + es[y0] + gacc + en[ylast];
    // ---- serial forward, scaled probability space; bpermute state broadcast
    float Ecol[K_];
#pragma unroll
    for (int i = 0; i < K_; i++) Ecol[i] = __expf(trs[i * K_ + jj]);
    float P = __expf(st[jj] + es[jj]);  // lanes >=19 duplicate state 18 (never read)
    int kacc = 0;
    float ee = __expf(es[K_ + jj]);  // exp(e) for t=1
    for (int t = 1; t < len; t++) {
      float pr[K_];
#pragma unroll
      for (int i = 0; i < K_; i++) pr[i] = bcast_f(P, i);
      int tn = (t + 1 < T_) ? t + 1 : T_ - 1;
      float e_next = es[tn * K_ + jj];  // prefetch (off chain)
      unsigned pb = __float_as_uint(pr[0]);
      int ex = (int)((pb >> 23) & 0xff);
      float scale = __uint_as_float((unsigned)(254 - ex) << 23);
      kacc += ex - 127;
      float a0 = 0.f, a1 = 0.f, a2 = 0.f, a3 = 0.f;
#pragma unroll
      for (int i = 0; i < K_; i++) {
        if ((i & 3) == 0)      a0 = fmaf(pr[i], Ecol[i], a0);
        else if ((i & 3) == 1) a1 = fmaf(pr[i], Ecol[i], a1);
        else if ((i & 3) == 2) a2 = fmaf(pr[i], Ecol[i], a2);
        else                   a3 = fmaf(pr[i], Ecol[i], a3);
      }
      P = (((a0 + a1) + (a2 + a3)) * ee) * scale;
      ee = __expf(e_next);  // off-chain: for step t+1
    }
    // final: logZ = log(sum P[i]*exp(en[i])) + kacc*ln2
    {
      float pr[K_];
#pragma unroll
      for (int i = 0; i < K_; i++) pr[i] = bcast_f(P, i);
      float sm = 0.f;
#pragma unroll
      for (int i = 0; i < K_; i++) sm += pr[i] * __expf(enr[i]);
      if (lane == 0) part[b] = __logf(sm) + (float)kacc * 0.6931471805599453f - num;
    }
    int old = -1;
    if (lane == 0) { __threadfence(); old = atomicAdd(cnt, 1); }
    old = __shfl(old, 0, 64);
    if (old == B_ - 1) {
      __threadfence();
      float s = 0.f;
      for (int u = lane; u < B_; u += 64) s += part[u];
#pragma unroll
      for (int off = 32; off; off >>= 1) s += __shfl_xor(s, off, 64);
      if (lane == 0) out[0] = s;
    }
  } else {
    // ---- Viterbi forward; bpermute state broadcast
    float Tt[K_];
#pragma unroll
    for (int i = 0; i < K_; i++) Tt[i] = trs[i * K_ + jj];
    float V = st[jj] + es[jj];
    float e = es[K_ + jj];  // emission for t=1 (unused if len==1)
    for (int t = 1; t < len; t++) {
      float vr[K_];
#pragma unroll
      for (int i = 0; i < K_; i++) vr[i] = bcast_f(V, i);
      int tn = (t + 1 < T_) ? t + 1 : T_ - 1;
      float e_next = es[tn * K_ + jj];  // prefetch (off chain)
      float b0 = -1e30f, b1 = -1e30f, b2 = -1e30f, b3 = -1e30f;
      int a0 = 0, a1 = 5, a2 = 10, a3 = 15;
#pragma unroll
      for (int i = 0; i < 5; i++)  { float c = vr[i] + Tt[i]; if (c > b0) { b0 = c; a0 = i; } }
#pragma unroll
      for (int i = 5; i < 10; i++) { float c = vr[i] + Tt[i]; if (c > b1) { b1 = c; a1 = i; } }
#pragma unroll
      for (int i = 10; i < 15; i++){ float c = vr[i] + Tt[i]; if (c > b2) { b2 = c; a2 = i; } }
#pragma unroll
      for (int i = 15; i < 19; i++){ float c = vr[i] + Tt[i]; if (c > b3) { b3 = c; a3 = i; } }
      if (b1 > b0) { b0 = b1; a0 = a1; }
      if (b2 > b0) { b0 = b2; a0 = a2; }
      if (b3 > b0) { b0 = b3; a0 = a3; }
      if (act) hl[(t - 1) * K_ + lane] = (unsigned char)a0;
      V = b0 + e;
      e = e_next;
    }
    // final argmax (first-max) over V + en
    int aa;
    {
      float vr[K_];
#pragma unroll
      for (int i = 0; i < K_; i++) vr[i] = bcast_f(V, i);
      float bb = vr[0] + enr[0]; aa = 0;
#pragma unroll
      for (int i = 1; i < K_; i++) {
        float c = vr[i] + enr[i];
        if (c > bb) { bb = c; aa = i; }
      }
    }
    // backtrack + direct label writes
    float* ob = out + 1 + (long)b * T_;
    for (int u = lane; u < T_; u += 64)
      if (u >= len) ob[u] = -1.f;
    int tag = aa;
    if (lane == 0) ob[len - 1] = (float)tag;
    int vc = (act && len >= 2) ? (int)hl[(len - 2) * K_ + lane] : 0;
    for (int ti = len - 2; ti >= 0; ti--) {
      int vn = 0;
      if (ti > 0 && act) vn = (int)hl[(ti - 1) * K_ + lane];
      int ts = __builtin_amdgcn_readfirstlane(tag);
      tag = __builtin_amdgcn_readlane(vc, ts);
      if (lane == 0) ob[ti] = (float)tag;
      vc = vn;
    }
  }
}

extern "C" void kernel_launch(void* const* d_in, const int* in_sizes, int n_in,
                              void* d_out, int out_size, void* d_ws, size_t ws_size,
                              hipStream_t stream) {
  const float* x      = (const float*)d_in[0];
  const int*   y      = (const int*)d_in[1];
  const float* w_ih_f = (const float*)d_in[2];
  const float* w_hh_f = (const float*)d_in[3];
  const float* b_ih_f = (const float*)d_in[4];
  const float* b_hh_f = (const float*)d_in[5];
  const float* w_ih_b = (const float*)d_in[6];
  const float* w_hh_b = (const float*)d_in[7];
  const float* b_ih_b = (const float*)d_in[8];
  const float* b_hh_b = (const float*)d_in[9];
  const float* w_lin  = (const float*)d_in[10];
  const float* b_lin  = (const float*)d_in[11];
  const float* st     = (const float*)d_in[12];
  const float* en     = (const float*)d_in[13];
  const float* trans  = (const float*)d_in[14];

  char* ws = (char*)d_ws;
  const size_t PRE_OFF  = 0;                          // 131072*200*4 = 104857600
  const size_t EM_OFF   = 104857600;                  // 131072*19*4  = 9961472
  const size_t PART_OFF = EM_OFF + 9961472;           // 1024
  const size_t CNT_OFF  = PART_OFF + 1024;            // 4
  float* PRE  = (float*)(ws + PRE_OFF);
  float* EM   = (float*)(ws + EM_OFF);
  float* PART = (float*)(ws + PART_OFF);
  int*   CNT  = (int*)(ws + CNT_OFF);
  unsigned short* W3 = (unsigned short*)(ws + EM_OFF);  // consumed before k_lin writes EM
  float* out  = (float*)d_out;

  hipMemsetAsync((void*)CNT, 0, sizeof(int), stream);
  k_wprep<<<196, 256, 0, stream>>>(w_ih_f, w_ih_b, W3);
  k_ih<<<512, 256, 0, stream>>>(x, W3, b_ih_f, b_hh_f, b_ih_b, b_hh_b, PRE);
  k_rnn<<<1024, 256, 0, stream>>>(PRE, w_hh_f, w_hh_b);
  k_lin<<<256, 256, 0, stream>>>(PRE, w_lin, b_lin, EM);
  k_crf<<<256, 128, 0, stream>>>(EM, y, st, en, trans, PART, CNT, out);
}

// Round 16
// 625.027 us; speedup vs baseline: 1.4978x; 1.0111x over previous
//
#include <hip/hip_runtime.h>
#include <hip/hip_bf16.h>

#define B_ 256
#define T_ 512
#define IN_ 202
#define HID_ 100
#define K_ 19

typedef __attribute__((ext_vector_type(8))) short short8v;
typedef __attribute__((ext_vector_type(4))) float f32x4;

__device__ __forceinline__ float rl_f(float v, int l) {
  return __int_as_float(__builtin_amdgcn_readlane(__float_as_int(v), l));
}
// register->register broadcast of lane l via LDS crossbar (no storage, no SGPR hazard)
__device__ __forceinline__ float bcast_f(float v, int l) {
  return __int_as_float(__builtin_amdgcn_ds_bpermute(l * 4, __float_as_int(v)));
}

// ---------------- K0: split [wf;wb] (200x202) into 3 exact bf16 planes, padded to 224x224.
__global__ __launch_bounds__(256, 1) void k_wprep(
    const float* __restrict__ wf, const float* __restrict__ wb,
    unsigned short* __restrict__ w3) {
  int idx = blockIdx.x * 256 + threadIdx.x;
  if (idx >= 224 * 224) return;
  int c = idx / 224, k = idx - (idx / 224) * 224;
  float v = 0.f;
  if (k < IN_) {
    if (c < 100) v = wf[c * IN_ + k];
    else if (c < 200) v = wb[(c - 100) * IN_ + k];
  }
  unsigned u0 = __float_as_uint(v) & 0xffff0000u;
  float r1 = v - __uint_as_float(u0);
  unsigned u1 = __float_as_uint(r1) & 0xffff0000u;
  float r2 = r1 - __uint_as_float(u1);
  w3[idx] = (unsigned short)(u0 >> 16);
  w3[50176 + idx] = (unsigned short)(u1 >> 16);
  w3[100352 + idx] = (unsigned short)(__float_as_uint(r2) >> 16);
}

// ---------------- K1: pre = x . [wf;wb]^T + bias via bf16-split MFMA (round-10 proven).
__global__ __launch_bounds__(256, 2) void k_ih(
    const float* __restrict__ x, const unsigned short* __restrict__ w3,
    const float* __restrict__ bif, const float* __restrict__ bhf,
    const float* __restrict__ bib, const float* __restrict__ bhb,
    float* __restrict__ pre) {
  __shared__ float xs[256 * 36];
  __shared__ float bsum[224];
  int tid = threadIdx.x;
  int wv = tid >> 6, l = tid & 63;
  long row0 = (long)blockIdx.x * 256;
  for (int u = tid; u < 224; u += 256) {
    float bv = 0.f;
    if (u < 100) bv = bif[u] + bhf[u];
    else if (u < 200) bv = bib[u - 100] + bhb[u - 100];
    bsum[u] = bv;
  }
  int lr = l & 15;
  int kq = l >> 4;
  for (int g = 0; g < 2; g++) {
    f32x4 acc[4][7];
#pragma unroll
    for (int m = 0; m < 4; m++)
#pragma unroll
      for (int n = 0; n < 7; n++) acc[m][n] = (f32x4){0.f, 0.f, 0.f, 0.f};
    for (int ck = 0; ck < 7; ck++) {
      int k0 = ck * 32;
      __syncthreads();
#pragma unroll
      for (int i = 0; i < 16; i++) {
        int u = tid + i * 256;
        int r = u >> 4, kp = u & 15;
        int gk = k0 + 2 * kp;
        float2 v = make_float2(0.f, 0.f);
        if (gk < IN_) v = *(const float2*)(x + (row0 + r) * IN_ + gk);
        *(float2*)(&xs[r * 36 + 2 * kp]) = v;
      }
      __syncthreads();
      short8v A0[4], A1[4], A2[4];
#pragma unroll
      for (int m = 0; m < 4; m++) {
        const float* ap = &xs[(wv * 64 + m * 16 + lr) * 36 + kq * 8];
        float4 fa = *(const float4*)(ap);
        float4 fb = *(const float4*)(ap + 4);
        float f[8] = {fa.x, fa.y, fa.z, fa.w, fb.x, fb.y, fb.z, fb.w};
#pragma unroll
        for (int j = 0; j < 8; j++) {
          unsigned u0 = __float_as_uint(f[j]) & 0xffff0000u;
          float r1 = f[j] - __uint_as_float(u0);
          unsigned u1 = __float_as_uint(r1) & 0xffff0000u;
          float r2 = r1 - __uint_as_float(u1);
          A0[m][j] = (short)(u0 >> 16);
          A1[m][j] = (short)(u1 >> 16);
          A2[m][j] = (short)(__float_as_uint(r2) >> 16);
        }
      }
#pragma unroll
      for (int n = 0; n < 7; n++) {
        int col = (g * 7 + n) * 16 + lr;
        const unsigned short* bp = w3 + (long)col * 224 + k0 + kq * 8;
        short8v B0 = *(const short8v*)(bp);
        short8v B1 = *(const short8v*)(bp + 50176);
        short8v B2 = *(const short8v*)(bp + 100352);
#pragma unroll
        for (int m = 0; m < 4; m++) {
          f32x4 c = acc[m][n];
          c = __builtin_amdgcn_mfma_f32_16x16x32_bf16(A0[m], B0, c, 0, 0, 0);
          c = __builtin_amdgcn_mfma_f32_16x16x32_bf16(A0[m], B1, c, 0, 0, 0);
          c = __builtin_amdgcn_mfma_f32_16x16x32_bf16(A1[m], B0, c, 0, 0, 0);
          c = __builtin_amdgcn_mfma_f32_16x16x32_bf16(A0[m], B2, c, 0, 0, 0);
          c = __builtin_amdgcn_mfma_f32_16x16x32_bf16(A2[m], B0, c, 0, 0, 0);
          c = __builtin_amdgcn_mfma_f32_16x16x32_bf16(A1[m], B1, c, 0, 0, 0);
          c = __builtin_amdgcn_mfma_f32_16x16x32_bf16(A1[m], B2, c, 0, 0, 0);
          c = __builtin_amdgcn_mfma_f32_16x16x32_bf16(A2[m], B1, c, 0, 0, 0);
          acc[m][n] = c;
        }
      }
    }
#pragma unroll
    for (int m = 0; m < 4; m++) {
      long rbase = row0 + wv * 64 + m * 16 + kq * 4;
#pragma unroll
      for (int n = 0; n < 7; n++) {
        int col = (g * 7 + n) * 16 + lr;
        if (col < 200) {
          float bv = bsum[col];
#pragma unroll
          for (int r = 0; r < 4; r++)
            pre[(rbase + r) * 200 + col] = acc[m][n][r] + bv;
        }
      }
    }
  }
}

// ---------------- K2: recurrence over b (256 steps); 8 waves per (t,dir) chain.
// Wave (grp,kq)=(wv&1,wv>>2? no: wv>>1): grp rows {0-63,64-99}, kq K-slices
// {[0,28),[28,52),[52,76),[76,100)}. Non-owners (kq!=0) deposit partials in
// ps[3][104]; owner (kq==0) sums + PRE + tanh, writes h. 2 barriers/step.
// 1024 blocks x 512 thr = 8192 waves -> 8 waves/SIMD (full occupancy).
template <int KO, int KN, bool OW>
__device__ __forceinline__ void rnn8(
    float* __restrict__ p, long step, int row, bool owns, int qidx,
    const float* __restrict__ w, float (*hb)[104], float (*ps)[104]) {
  float wr[KN];
#pragma unroll
  for (int i = 0; i < KN / 4; i++) {
    float4 w4 = *(const float4*)(w + row * HID_ + KO + 4 * i);
    wr[4 * i + 0] = w4.x; wr[4 * i + 1] = w4.y;
    wr[4 * i + 2] = w4.z; wr[4 * i + 3] = w4.w;
  }
  float a = 0.f;
  if (OW) a = p[row];
  for (int s = 0; s < B_; s++) {
    int cur = s & 1;
    float a_next = 0.f;
    if (OW && s < B_ - 1) a_next = p[step + row];
    float ac0 = OW ? a : 0.f, ac1 = 0.f, ac2 = 0.f, ac3 = 0.f;
#pragma unroll
    for (int i = 0; i < KN / 4; i++) {
      float4 h4 = *(const float4*)(&hb[cur][KO + 4 * i]);  // uniform -> broadcast
      ac0 = fmaf(h4.x, wr[4 * i + 0], ac0);
      ac1 = fmaf(h4.y, wr[4 * i + 1], ac1);
      ac2 = fmaf(h4.z, wr[4 * i + 2], ac2);
      ac3 = fmaf(h4.w, wr[4 * i + 3], ac3);
    }
    float partial = (ac0 + ac1) + (ac2 + ac3);
    if (!OW && owns) ps[qidx][row] = partial;
    __syncthreads();
    if (OW) {
      float tot = partial + ps[0][row] + ps[1][row] + ps[2][row];
      float hnew = tanhf(tot);
      if (owns) {
        p[row] = hnew;
        hb[cur ^ 1][row] = hnew;
      }
    }
    __syncthreads();
    p += step;
    a = a_next;
  }
}

__global__ __launch_bounds__(512, 8) void k_rnn(
    float* __restrict__ pre,
    const float* __restrict__ whf, const float* __restrict__ whb) {
  __shared__ __align__(16) float hb[2][104];
  __shared__ __align__(16) float ps[3][104];
  int bid = blockIdx.x;
  int dir = bid >> 9;
  int t = bid & 511;
  const float* w = dir ? whb : whf;
  int tid = threadIdx.x;
  int wv = tid >> 6, lane = tid & 63;
  int grp = wv & 1;     // 0: rows 0..63, 1: rows 64..99
  int kq = wv >> 1;     // K slice 0..3 (0 = owner)
  int row = grp ? (64 + (lane < 36 ? lane : 35)) : lane;
  bool owns = grp ? (lane < 36) : true;
  long step = dir ? -(long)(T_ * 200) : (long)(T_ * 200);
  float* p = pre + ((long)(dir ? (B_ - 1) : 0) * T_ + t) * 200 + dir * 100;
  if (tid < 104) hb[0][tid] = 0.f;
  __syncthreads();
  if (kq == 0)      rnn8<0, 28, true >(p, step, row, owns, 0, w, hb, ps);
  else if (kq == 1) rnn8<28, 24, false>(p, step, row, owns, 0, w, hb, ps);
  else if (kq == 2) rnn8<52, 24, false>(p, step, row, owns, 1, w, hb, ps);
  else              rnn8<76, 24, false>(p, step, row, owns, 2, w, hb, ps);
}

// ---------------- K3: logits = h @ w_lin^T + b_lin ; softmax over 19. 2 rows/thread.
__global__ __launch_bounds__(256, 4) void k_lin(
    const float* __restrict__ h, const float* __restrict__ wlin,
    const float* __restrict__ blin, float* __restrict__ em) {
  int tid = threadIdx.x;
  long r0 = ((long)blockIdx.x * 256 + tid) * 2;
  const float* h0 = h + r0 * 200;
  float acc0[K_], acc1[K_];
#pragma unroll
  for (int c = 0; c < K_; c++) { float bb = blin[c]; acc0[c] = bb; acc1[c] = bb; }
  for (int kk = 0; kk < 50; kk++) {
    float4 a = *(const float4*)(h0 + 4 * kk);
    float4 b = *(const float4*)(h0 + 200 + 4 * kk);
#pragma unroll
    for (int c = 0; c < K_; c++) {
      float4 wv = *(const float4*)(wlin + c * 200 + 4 * kk);
      acc0[c] += a.x * wv.x + a.y * wv.y + a.z * wv.z + a.w * wv.w;
      acc1[c] += b.x * wv.x + b.y * wv.y + b.z * wv.z + b.w * wv.w;
    }
  }
  float mx0 = acc0[0], mx1 = acc1[0];
#pragma unroll
  for (int c = 1; c < K_; c++) { mx0 = fmaxf(mx0, acc0[c]); mx1 = fmaxf(mx1, acc1[c]); }
  float s0 = 0.f, s1 = 0.f;
#pragma unroll
  for (int c = 0; c < K_; c++) {
    acc0[c] = __expf(acc0[c] - mx0); s0 += acc0[c];
    acc1[c] = __expf(acc1[c] - mx1); s1 += acc1[c];
  }
  float i0 = 1.f / s0, i1 = 1.f / s1;
  float* e0 = em + r0 * K_;
#pragma unroll
  for (int c = 0; c < K_; c++) { e0[c] = acc0[c] * i0; e0[K_ + c] = acc1[c] * i1; }
}

// ---------------- K4: 2 waves per b; bpermute state broadcast (round-15 proven).
__global__ __launch_bounds__(128, 1) void k_crf(
    const float* __restrict__ em, const int* __restrict__ y,
    const float* __restrict__ st_g, const float* __restrict__ en_g,
    const float* __restrict__ tr_g,
    float* __restrict__ part, int* __restrict__ cnt,
    float* __restrict__ out) {
  __shared__ __align__(16) float es[T_ * K_];
  __shared__ int ys[T_];
  __shared__ float trs[K_ * K_];
  __shared__ float st[K_], en[K_];
  __shared__ unsigned char hl[511 * K_ + 13];
  int b = blockIdx.x;
  int tid = threadIdx.x;
  int wv = tid >> 6, lane = tid & 63;
  const float4* eb4 = (const float4*)(em + (long)b * T_ * K_);
  for (int u = tid; u < T_ * K_ / 4; u += 128) ((float4*)es)[u] = eb4[u];
  for (int u = tid; u < T_; u += 128) ys[u] = y[b * T_ + u];
  for (int u = tid; u < K_ * K_; u += 128) trs[u] = tr_g[u];
  if (tid < K_) { st[tid] = st_g[tid]; en[tid] = en_g[tid]; }
  __syncthreads();
  int lmin = T_;
  for (int u = lane; u < T_; u += 64)
    if (ys[u] == -1 && u < lmin) lmin = u;
#pragma unroll
  for (int off = 32; off; off >>= 1) {
    int o = __shfl_xor(lmin, off, 64);
    lmin = lmin < o ? lmin : o;
  }
  int len = lmin;  // >= 1

  int jj = lane < K_ ? lane : K_ - 1;
  bool act = lane < K_;
  float enr[20];
#pragma unroll
  for (int q = 0; q < 5; q++) {
    float4 e4 = (q < 4) ? *(const float4*)(&en[4 * q])
                        : make_float4(en[16], en[17], en[18], -1e30f);
    enr[4 * q] = e4.x; enr[4 * q + 1] = e4.y; enr[4 * q + 2] = e4.z; enr[4 * q + 3] = e4.w;
  }

  if (wv == 0) {
    float gacc = 0.f;
    for (int t = 1 + lane; t < len; t += 64)
      gacc += trs[ys[t - 1] * K_ + ys[t]] + es[t * K_ + ys[t]];
#pragma unroll
    for (int off = 32; off; off >>= 1) gacc += __shfl_xor(gacc, off, 64);
    int y0 = ys[0], ylast = ys[len - 1];
    float num = st[y0] + es[y0] + gacc + en[ylast];
    float Ecol[K_];
#pragma unroll
    for (int i = 0; i < K_; i++) Ecol[i] = __expf(trs[i * K_ + jj]);
    float P = __expf(st[jj] + es[jj]);
    int kacc = 0;
    float ee = __expf(es[K_ + jj]);
    for (int t = 1; t < len; t++) {
      float pr[K_];
#pragma unroll
      for (int i = 0; i < K_; i++) pr[i] = bcast_f(P, i);
      int tn = (t + 1 < T_) ? t + 1 : T_ - 1;
      float e_next = es[tn * K_ + jj];
      unsigned pb = __float_as_uint(pr[0]);
      int ex = (int)((pb >> 23) & 0xff);
      float scale = __uint_as_float((unsigned)(254 - ex) << 23);
      kacc += ex - 127;
      float a0 = 0.f, a1 = 0.f, a2 = 0.f, a3 = 0.f;
#pragma unroll
      for (int i = 0; i < K_; i++) {
        if ((i & 3) == 0)      a0 = fmaf(pr[i], Ecol[i], a0);
        else if ((i & 3) == 1) a1 = fmaf(pr[i], Ecol[i], a1);
        else if ((i & 3) == 2) a2 = fmaf(pr[i], Ecol[i], a2);
        else                   a3 = fmaf(pr[i], Ecol[i], a3);
      }
      P = (((a0 + a1) + (a2 + a3)) * ee) * scale;
      ee = __expf(e_next);
    }
    {
      float pr[K_];
#pragma unroll
      for (int i = 0; i < K_; i++) pr[i] = bcast_f(P, i);
      float sm = 0.f;
#pragma unroll
      for (int i = 0; i < K_; i++) sm += pr[i] * __expf(enr[i]);
      if (lane == 0) part[b] = __logf(sm) + (float)kacc * 0.6931471805599453f - num;
    }
    int old = -1;
    if (lane == 0) { __threadfence(); old = atomicAdd(cnt, 1); }
    old = __shfl(old, 0, 64);
    if (old == B_ - 1) {
      __threadfence();
      float s = 0.f;
      for (int u = lane; u < B_; u += 64) s += part[u];
#pragma unroll
      for (int off = 32; off; off >>= 1) s += __shfl_xor(s, off, 64);
      if (lane == 0) out[0] = s;
    }
  } else {
    float Tt[K_];
#pragma unroll
    for (int i = 0; i < K_; i++) Tt[i] = trs[i * K_ + jj];
    float V = st[jj] + es[jj];
    float e = es[K_ + jj];
    for (int t = 1; t < len; t++) {
      float vr[K_];
#pragma unroll
      for (int i = 0; i < K_; i++) vr[i] = bcast_f(V, i);
      int tn = (t + 1 < T_) ? t + 1 : T_ - 1;
      float e_next = es[tn * K_ + jj];
      float b0 = -1e30f, b1 = -1e30f, b2 = -1e30f, b3 = -1e30f;
      int a0 = 0, a1 = 5, a2 = 10, a3 = 15;
#pragma unroll
      for (int i = 0; i < 5; i++)  { float c = vr[i] + Tt[i]; if (c > b0) { b0 = c; a0 = i; } }
#pragma unroll
      for (int i = 5; i < 10; i++) { float c = vr[i] + Tt[i]; if (c > b1) { b1 = c; a1 = i; } }
#pragma unroll
      for (int i = 10; i < 15; i++){ float c = vr[i] + Tt[i]; if (c > b2) { b2 = c; a2 = i; } }
#pragma unroll
      for (int i = 15; i < 19; i++){ float c = vr[i] + Tt[i]; if (c > b3) { b3 = c; a3 = i; } }
      if (b1 > b0) { b0 = b1; a0 = a1; }
      if (b2 > b0) { b0 = b2; a0 = a2; }
      if (b3 > b0) { b0 = b3; a0 = a3; }
      if (act) hl[(t - 1) * K_ + lane] = (unsigned char)a0;
      V = b0 + e;
      e = e_next;
    }
    int aa;
    {
      float vr[K_];
#pragma unroll
      for (int i = 0; i < K_; i++) vr[i] = bcast_f(V, i);
      float bb = vr[0] + enr[0]; aa = 0;
#pragma unroll
      for (int i = 1; i < K_; i++) {
        float c = vr[i] + enr[i];
        if (c > bb) { bb = c; aa = i; }
      }
    }
    float* ob = out + 1 + (long)b * T_;
    for (int u = lane; u < T_; u += 64)
      if (u >= len) ob[u] = -1.f;
    int tag = aa;
    if (lane == 0) ob[len - 1] = (float)tag;
    int vc = (act && len >= 2) ? (int)hl[(len - 2) * K_ + lane] : 0;
    for (int ti = len - 2; ti >= 0; ti--) {
      int vn = 0;
      if (ti > 0 && act) vn = (int)hl[(ti - 1) * K_ + lane];
      int ts = __builtin_amdgcn_readfirstlane(tag);
      tag = __builtin_amdgcn_readlane(vc, ts);
      if (lane == 0) ob[ti] = (float)tag;
      vc = vn;
    }
  }
}

extern "C" void kernel_launch(void* const* d_in, const int* in_sizes, int n_in,
                              void* d_out, int out_size, void* d_ws, size_t ws_size,
                              hipStream_t stream) {
  const float* x      = (const float*)d_in[0];
  const int*   y      = (const int*)d_in[1];
  const float* w_ih_f = (const float*)d_in[2];
  const float* w_hh_f = (const float*)d_in[3];
  const float* b_ih_f = (const float*)d_in[4];
  const float* b_hh_f = (const float*)d_in[5];
  const float* w_ih_b = (const float*)d_in[6];
  const float* w_hh_b = (const float*)d_in[7];
  const float* b_ih_b = (const float*)d_in[8];
  const float* b_hh_b = (const float*)d_in[9];
  const float* w_lin  = (const float*)d_in[10];
  const float* b_lin  = (const float*)d_in[11];
  const float* st     = (const float*)d_in[12];
  const float* en     = (const float*)d_in[13];
  const float* trans  = (const float*)d_in[14];

  char* ws = (char*)d_ws;
  const size_t PRE_OFF  = 0;                          // 131072*200*4 = 104857600
  const size_t EM_OFF   = 104857600;                  // 131072*19*4  = 9961472
  const size_t PART_OFF = EM_OFF + 9961472;           // 1024
  const size_t CNT_OFF  = PART_OFF + 1024;            // 4
  float* PRE  = (float*)(ws + PRE_OFF);
  float* EM   = (float*)(ws + EM_OFF);
  float* PART = (float*)(ws + PART_OFF);
  int*   CNT  = (int*)(ws + CNT_OFF);
  unsigned short* W3 = (unsigned short*)(ws + EM_OFF);  // consumed before k_lin writes EM
  float* out  = (float*)d_out;

  hipMemsetAsync((void*)CNT, 0, sizeof(int), stream);
  k_wprep<<<196, 256, 0, stream>>>(w_ih_f, w_ih_b, W3);
  k_ih<<<512, 256, 0, stream>>>(x, W3, b_ih_f, b_hh_f, b_ih_b, b_hh_b, PRE);
  k_rnn<<<1024, 512, 0, stream>>>(PRE, w_hh_f, w_hh_b);
  k_lin<<<256, 256, 0, stream>>>(PRE, w_lin, b_lin, EM);
  k_crf<<<256, 128, 0, stream>>>(EM, y, st, en, trans, PART, CNT, out);
}

// Round 17
// 605.582 us; speedup vs baseline: 1.5459x; 1.0321x over previous
//
#include <hip/hip_runtime.h>
#include <hip/hip_bf16.h>

#define B_ 256
#define T_ 512
#define IN_ 202
#define HID_ 100
#define K_ 19

typedef __attribute__((ext_vector_type(8))) short short8v;
typedef __attribute__((ext_vector_type(4))) float f32x4;

__device__ __forceinline__ float rl_f(float v, int l) {
  return __int_as_float(__builtin_amdgcn_readlane(__float_as_int(v), l));
}
// register->register broadcast of lane l via LDS crossbar (no storage, no SGPR hazard)
__device__ __forceinline__ float bcast_f(float v, int l) {
  return __int_as_float(__builtin_amdgcn_ds_bpermute(l * 4, __float_as_int(v)));
}
// tanh(x) = 1 - 2/(exp(2x)+1): 5 instrs vs ~25 for libm; exact saturation at +-1.
__device__ __forceinline__ float fast_tanh(float x) {
  float t = __expf(2.f * x);
  float r = __builtin_amdgcn_rcpf(t + 1.f);
  return fmaf(-2.f, r, 1.f);
}

// ---------------- K0: split [wf;wb] (200x202) into 3 exact bf16 planes, padded to 224x224.
__global__ __launch_bounds__(256, 1) void k_wprep(
    const float* __restrict__ wf, const float* __restrict__ wb,
    unsigned short* __restrict__ w3) {
  int idx = blockIdx.x * 256 + threadIdx.x;
  if (idx >= 224 * 224) return;
  int c = idx / 224, k = idx - (idx / 224) * 224;
  float v = 0.f;
  if (k < IN_) {
    if (c < 100) v = wf[c * IN_ + k];
    else if (c < 200) v = wb[(c - 100) * IN_ + k];
  }
  unsigned u0 = __float_as_uint(v) & 0xffff0000u;
  float r1 = v - __uint_as_float(u0);
  unsigned u1 = __float_as_uint(r1) & 0xffff0000u;
  float r2 = r1 - __uint_as_float(u1);
  w3[idx] = (unsigned short)(u0 >> 16);
  w3[50176 + idx] = (unsigned short)(u1 >> 16);
  w3[100352 + idx] = (unsigned short)(__float_as_uint(r2) >> 16);
}

// ---------------- K1: pre = x . [wf;wb]^T + bias via bf16-split MFMA (round-10 proven).
__global__ __launch_bounds__(256, 2) void k_ih(
    const float* __restrict__ x, const unsigned short* __restrict__ w3,
    const float* __restrict__ bif, const float* __restrict__ bhf,
    const float* __restrict__ bib, const float* __restrict__ bhb,
    float* __restrict__ pre) {
  __shared__ float xs[256 * 36];
  __shared__ float bsum[224];
  int tid = threadIdx.x;
  int wv = tid >> 6, l = tid & 63;
  long row0 = (long)blockIdx.x * 256;
  for (int u = tid; u < 224; u += 256) {
    float bv = 0.f;
    if (u < 100) bv = bif[u] + bhf[u];
    else if (u < 200) bv = bib[u - 100] + bhb[u - 100];
    bsum[u] = bv;
  }
  int lr = l & 15;
  int kq = l >> 4;
  for (int g = 0; g < 2; g++) {
    f32x4 acc[4][7];
#pragma unroll
    for (int m = 0; m < 4; m++)
#pragma unroll
      for (int n = 0; n < 7; n++) acc[m][n] = (f32x4){0.f, 0.f, 0.f, 0.f};
    for (int ck = 0; ck < 7; ck++) {
      int k0 = ck * 32;
      __syncthreads();
#pragma unroll
      for (int i = 0; i < 16; i++) {
        int u = tid + i * 256;
        int r = u >> 4, kp = u & 15;
        int gk = k0 + 2 * kp;
        float2 v = make_float2(0.f, 0.f);
        if (gk < IN_) v = *(const float2*)(x + (row0 + r) * IN_ + gk);
        *(float2*)(&xs[r * 36 + 2 * kp]) = v;
      }
      __syncthreads();
      short8v A0[4], A1[4], A2[4];
#pragma unroll
      for (int m = 0; m < 4; m++) {
        const float* ap = &xs[(wv * 64 + m * 16 + lr) * 36 + kq * 8];
        float4 fa = *(const float4*)(ap);
        float4 fb = *(const float4*)(ap + 4);
        float f[8] = {fa.x, fa.y, fa.z, fa.w, fb.x, fb.y, fb.z, fb.w};
#pragma unroll
        for (int j = 0; j < 8; j++) {
          unsigned u0 = __float_as_uint(f[j]) & 0xffff0000u;
          float r1 = f[j] - __uint_as_float(u0);
          unsigned u1 = __float_as_uint(r1) & 0xffff0000u;
          float r2 = r1 - __uint_as_float(u1);
          A0[m][j] = (short)(u0 >> 16);
          A1[m][j] = (short)(u1 >> 16);
          A2[m][j] = (short)(__float_as_uint(r2) >> 16);
        }
      }
#pragma unroll
      for (int n = 0; n < 7; n++) {
        int col = (g * 7 + n) * 16 + lr;
        const unsigned short* bp = w3 + (long)col * 224 + k0 + kq * 8;
        short8v B0 = *(const short8v*)(bp);
        short8v B1 = *(const short8v*)(bp + 50176);
        short8v B2 = *(const short8v*)(bp + 100352);
#pragma unroll
        for (int m = 0; m < 4; m++) {
          f32x4 c = acc[m][n];
          c = __builtin_amdgcn_mfma_f32_16x16x32_bf16(A0[m], B0, c, 0, 0, 0);
          c = __builtin_amdgcn_mfma_f32_16x16x32_bf16(A0[m], B1, c, 0, 0, 0);
          c = __builtin_amdgcn_mfma_f32_16x16x32_bf16(A1[m], B0, c, 0, 0, 0);
          c = __builtin_amdgcn_mfma_f32_16x16x32_bf16(A0[m], B2, c, 0, 0, 0);
          c = __builtin_amdgcn_mfma_f32_16x16x32_bf16(A2[m], B0, c, 0, 0, 0);
          c = __builtin_amdgcn_mfma_f32_16x16x32_bf16(A1[m], B1, c, 0, 0, 0);
          c = __builtin_amdgcn_mfma_f32_16x16x32_bf16(A1[m], B2, c, 0, 0, 0);
          c = __builtin_amdgcn_mfma_f32_16x16x32_bf16(A2[m], B1, c, 0, 0, 0);
          acc[m][n] = c;
        }
      }
    }
#pragma unroll
    for (int m = 0; m < 4; m++) {
      long rbase = row0 + wv * 64 + m * 16 + kq * 4;
#pragma unroll
      for (int n = 0; n < 7; n++) {
        int col = (g * 7 + n) * 16 + lr;
        if (col < 200) {
          float bv = bsum[col];
#pragma unroll
          for (int r = 0; r < 4; r++)
            pre[(rbase + r) * 200 + col] = acc[m][n][r] + bv;
        }
      }
    }
  }
}

// ---------------- K2: recurrence over b (256 steps); 8 waves per (t,dir) chain.
// K-slices BALANCED {16,28,28,28} (owner kq=0 gets 16 + sum/tanh/store duty).
// Fast tanh (exp-form). 2 barriers/step. 1024 blocks x 512 thr.
template <int KO, int KN, bool OW>
__device__ __forceinline__ void rnn8(
    float* __restrict__ p, long step, int row, bool owns, int qidx,
    const float* __restrict__ w, float (*hb)[104], float (*ps)[104]) {
  float wr[KN];
#pragma unroll
  for (int i = 0; i < KN / 4; i++) {
    float4 w4 = *(const float4*)(w + row * HID_ + KO + 4 * i);
    wr[4 * i + 0] = w4.x; wr[4 * i + 1] = w4.y;
    wr[4 * i + 2] = w4.z; wr[4 * i + 3] = w4.w;
  }
  float a = 0.f;
  if (OW) a = p[row];
  for (int s = 0; s < B_; s++) {
    int cur = s & 1;
    float a_next = 0.f;
    if (OW && s < B_ - 1) a_next = p[step + row];
    float ac0 = OW ? a : 0.f, ac1 = 0.f, ac2 = 0.f, ac3 = 0.f;
#pragma unroll
    for (int i = 0; i < KN / 4; i++) {
      float4 h4 = *(const float4*)(&hb[cur][KO + 4 * i]);  // uniform -> broadcast
      ac0 = fmaf(h4.x, wr[4 * i + 0], ac0);
      ac1 = fmaf(h4.y, wr[4 * i + 1], ac1);
      ac2 = fmaf(h4.z, wr[4 * i + 2], ac2);
      ac3 = fmaf(h4.w, wr[4 * i + 3], ac3);
    }
    float partial = (ac0 + ac1) + (ac2 + ac3);
    if (!OW && owns) ps[qidx][row] = partial;
    __syncthreads();
    if (OW) {
      float tot = partial + ps[0][row] + ps[1][row] + ps[2][row];
      float hnew = fast_tanh(tot);
      if (owns) {
        p[row] = hnew;
        hb[cur ^ 1][row] = hnew;
      }
    }
    __syncthreads();
    p += step;
    a = a_next;
  }
}

__global__ __launch_bounds__(512, 8) void k_rnn(
    float* __restrict__ pre,
    const float* __restrict__ whf, const float* __restrict__ whb) {
  __shared__ __align__(16) float hb[2][104];
  __shared__ __align__(16) float ps[3][104];
  int bid = blockIdx.x;
  int dir = bid >> 9;
  int t = bid & 511;
  const float* w = dir ? whb : whf;
  int tid = threadIdx.x;
  int wv = tid >> 6, lane = tid & 63;
  int grp = wv & 1;     // 0: rows 0..63, 1: rows 64..99
  int kq = wv >> 1;     // K slice 0..3 (0 = owner)
  int row = grp ? (64 + (lane < 36 ? lane : 35)) : lane;
  bool owns = grp ? (lane < 36) : true;
  long step = dir ? -(long)(T_ * 200) : (long)(T_ * 200);
  float* p = pre + ((long)(dir ? (B_ - 1) : 0) * T_ + t) * 200 + dir * 100;
  if (tid < 104) hb[0][tid] = 0.f;
  __syncthreads();
  if (kq == 0)      rnn8<0, 16, true >(p, step, row, owns, 0, w, hb, ps);
  else if (kq == 1) rnn8<16, 28, false>(p, step, row, owns, 0, w, hb, ps);
  else if (kq == 2) rnn8<44, 28, false>(p, step, row, owns, 1, w, hb, ps);
  else              rnn8<72, 28, false>(p, step, row, owns, 2, w, hb, ps);
}

// ---------------- K3: logits = h @ w_lin^T + b_lin ; softmax over 19. 2 rows/thread.
__global__ __launch_bounds__(256, 4) void k_lin(
    const float* __restrict__ h, const float* __restrict__ wlin,
    const float* __restrict__ blin, float* __restrict__ em) {
  int tid = threadIdx.x;
  long r0 = ((long)blockIdx.x * 256 + tid) * 2;
  const float* h0 = h + r0 * 200;
  float acc0[K_], acc1[K_];
#pragma unroll
  for (int c = 0; c < K_; c++) { float bb = blin[c]; acc0[c] = bb; acc1[c] = bb; }
  for (int kk = 0; kk < 50; kk++) {
    float4 a = *(const float4*)(h0 + 4 * kk);
    float4 b = *(const float4*)(h0 + 200 + 4 * kk);
#pragma unroll
    for (int c = 0; c < K_; c++) {
      float4 wv = *(const float4*)(wlin + c * 200 + 4 * kk);
      acc0[c] += a.x * wv.x + a.y * wv.y + a.z * wv.z + a.w * wv.w;
      acc1[c] += b.x * wv.x + b.y * wv.y + b.z * wv.z + b.w * wv.w;
    }
  }
  float mx0 = acc0[0], mx1 = acc1[0];
#pragma unroll
  for (int c = 1; c < K_; c++) { mx0 = fmaxf(mx0, acc0[c]); mx1 = fmaxf(mx1, acc1[c]); }
  float s0 = 0.f, s1 = 0.f;
#pragma unroll
  for (int c = 0; c < K_; c++) {
    acc0[c] = __expf(acc0[c] - mx0); s0 += acc0[c];
    acc1[c] = __expf(acc1[c] - mx1); s1 += acc1[c];
  }
  float i0 = 1.f / s0, i1 = 1.f / s1;
  float* e0 = em + r0 * K_;
#pragma unroll
  for (int c = 0; c < K_; c++) { e0[c] = acc0[c] * i0; e0[K_ + c] = acc1[c] * i1; }
}

// ---------------- K4: 2 waves per b; bpermute state broadcast (round-15 proven).
__global__ __launch_bounds__(128, 1) void k_crf(
    const float* __restrict__ em, const int* __restrict__ y,
    const float* __restrict__ st_g, const float* __restrict__ en_g,
    const float* __restrict__ tr_g,
    float* __restrict__ part, int* __restrict__ cnt,
    float* __restrict__ out) {
  __shared__ __align__(16) float es[T_ * K_];
  __shared__ int ys[T_];
  __shared__ float trs[K_ * K_];
  __shared__ float st[K_], en[K_];
  __shared__ unsigned char hl[511 * K_ + 13];
  int b = blockIdx.x;
  int tid = threadIdx.x;
  int wv = tid >> 6, lane = tid & 63;
  const float4* eb4 = (const float4*)(em + (long)b * T_ * K_);
  for (int u = tid; u < T_ * K_ / 4; u += 128) ((float4*)es)[u] = eb4[u];
  for (int u = tid; u < T_; u += 128) ys[u] = y[b * T_ + u];
  for (int u = tid; u < K_ * K_; u += 128) trs[u] = tr_g[u];
  if (tid < K_) { st[tid] = st_g[tid]; en[tid] = en_g[tid]; }
  __syncthreads();
  int lmin = T_;
  for (int u = lane; u < T_; u += 64)
    if (ys[u] == -1 && u < lmin) lmin = u;
#pragma unroll
  for (int off = 32; off; off >>= 1) {
    int o = __shfl_xor(lmin, off, 64);
    lmin = lmin < o ? lmin : o;
  }
  int len = lmin;  // >= 1

  int jj = lane < K_ ? lane : K_ - 1;
  bool act = lane < K_;
  float enr[20];
#pragma unroll
  for (int q = 0; q < 5; q++) {
    float4 e4 = (q < 4) ? *(const float4*)(&en[4 * q])
                        : make_float4(en[16], en[17], en[18], -1e30f);
    enr[4 * q] = e4.x; enr[4 * q + 1] = e4.y; enr[4 * q + 2] = e4.z; enr[4 * q + 3] = e4.w;
  }

  if (wv == 0) {
    float gacc = 0.f;
    for (int t = 1 + lane; t < len; t += 64)
      gacc += trs[ys[t - 1] * K_ + ys[t]] + es[t * K_ + ys[t]];
#pragma unroll
    for (int off = 32; off; off >>= 1) gacc += __shfl_xor(gacc, off, 64);
    int y0 = ys[0], ylast = ys[len - 1];
    float num = st[y0] + es[y0] + gacc + en[ylast];
    float Ecol[K_];
#pragma unroll
    for (int i = 0; i < K_; i++) Ecol[i] = __expf(trs[i * K_ + jj]);
    float P = __expf(st[jj] + es[jj]);
    int kacc = 0;
    float ee = __expf(es[K_ + jj]);
    for (int t = 1; t < len; t++) {
      float pr[K_];
#pragma unroll
      for (int i = 0; i < K_; i++) pr[i] = bcast_f(P, i);
      int tn = (t + 1 < T_) ? t + 1 : T_ - 1;
      float e_next = es[tn * K_ + jj];
      unsigned pb = __float_as_uint(pr[0]);
      int ex = (int)((pb >> 23) & 0xff);
      float scale = __uint_as_float((unsigned)(254 - ex) << 23);
      kacc += ex - 127;
      float a0 = 0.f, a1 = 0.f, a2 = 0.f, a3 = 0.f;
#pragma unroll
      for (int i = 0; i < K_; i++) {
        if ((i & 3) == 0)      a0 = fmaf(pr[i], Ecol[i], a0);
        else if ((i & 3) == 1) a1 = fmaf(pr[i], Ecol[i], a1);
        else if ((i & 3) == 2) a2 = fmaf(pr[i], Ecol[i], a2);
        else                   a3 = fmaf(pr[i], Ecol[i], a3);
      }
      P = (((a0 + a1) + (a2 + a3)) * ee) * scale;
      ee = __expf(e_next);
    }
    {
      float pr[K_];
#pragma unroll
      for (int i = 0; i < K_; i++) pr[i] = bcast_f(P, i);
      float sm = 0.f;
#pragma unroll
      for (int i = 0; i < K_; i++) sm += pr[i] * __expf(enr[i]);
      if (lane == 0) part[b] = __logf(sm) + (float)kacc * 0.6931471805599453f - num;
    }
    int old = -1;
    if (lane == 0) { __threadfence(); old = atomicAdd(cnt, 1); }
    old = __shfl(old, 0, 64);
    if (old == B_ - 1) {
      __threadfence();
      float s = 0.f;
      for (int u = lane; u < B_; u += 64) s += part[u];
#pragma unroll
      for (int off = 32; off; off >>= 1) s += __shfl_xor(s, off, 64);
      if (lane == 0) out[0] = s;
    }
  } else {
    float Tt[K_];
#pragma unroll
    for (int i = 0; i < K_; i++) Tt[i] = trs[i * K_ + jj];
    float V = st[jj] + es[jj];
    float e = es[K_ + jj];
    for (int t = 1; t < len; t++) {
      float vr[K_];
#pragma unroll
      for (int i = 0; i < K_; i++) vr[i] = bcast_f(V, i);
      int tn = (t + 1 < T_) ? t + 1 : T_ - 1;
      float e_next = es[tn * K_ + jj];
      float b0 = -1e30f, b1 = -1e30f, b2 = -1e30f, b3 = -1e30f;
      int a0 = 0, a1 = 5, a2 = 10, a3 = 15;
#pragma unroll
      for (int i = 0; i < 5; i++)  { float c = vr[i] + Tt[i]; if (c > b0) { b0 = c; a0 = i; } }
#pragma unroll
      for (int i = 5; i < 10; i++) { float c = vr[i] + Tt[i]; if (c > b1) { b1 = c; a1 = i; } }
#pragma unroll
      for (int i = 10; i < 15; i++){ float c = vr[i] + Tt[i]; if (c > b2) { b2 = c; a2 = i; } }
#pragma unroll
      for (int i = 15; i < 19; i++){ float c = vr[i] + Tt[i]; if (c > b3) { b3 = c; a3 = i; } }
      if (b1 > b0) { b0 = b1; a0 = a1; }
      if (b2 > b0) { b0 = b2; a0 = a2; }
      if (b3 > b0) { b0 = b3; a0 = a3; }
      if (act) hl[(t - 1) * K_ + lane] = (unsigned char)a0;
      V = b0 + e;
      e = e_next;
    }
    int aa;
    {
      float vr[K_];
#pragma unroll
      for (int i = 0; i < K_; i++) vr[i] = bcast_f(V, i);
      float bb = vr[0] + enr[0]; aa = 0;
#pragma unroll
      for (int i = 1; i < K_; i++) {
        float c = vr[i] + enr[i];
        if (c > bb) { bb = c; aa = i; }
      }
    }
    float* ob = out + 1 + (long)b * T_;
    for (int u = lane; u < T_; u += 64)
      if (u >= len) ob[u] = -1.f;
    int tag = aa;
    if (lane == 0) ob[len - 1] = (float)tag;
    int vc = (act && len >= 2) ? (int)hl[(len - 2) * K_ + lane] : 0;
    for (int ti = len - 2; ti >= 0; ti--) {
      int vn = 0;
      if (ti > 0 && act) vn = (int)hl[(ti - 1) * K_ + lane];
      int ts = __builtin_amdgcn_readfirstlane(tag);
      tag = __builtin_amdgcn_readlane(vc, ts);
      if (lane == 0) ob[ti] = (float)tag;
      vc = vn;
    }
  }
}

extern "C" void kernel_launch(void* const* d_in, const int* in_sizes, int n_in,
                              void* d_out, int out_size, void* d_ws, size_t ws_size,
                              hipStream_t stream) {
  const float* x      = (const float*)d_in[0];
  const int*   y      = (const int*)d_in[1];
  const float* w_ih_f = (const float*)d_in[2];
  const float* w_hh_f = (const float*)d_in[3];
  const float* b_ih_f = (const float*)d_in[4];
  const float* b_hh_f = (const float*)d_in[5];
  const float* w_ih_b = (const float*)d_in[6];
  const float* w_hh_b = (const float*)d_in[7];
  const float* b_ih_b = (const float*)d_in[8];
  const float* b_hh_b = (const float*)d_in[9];
  const float* w_lin  = (const float*)d_in[10];
  const float* b_lin  = (const float*)d_in[11];
  const float* st     = (const float*)d_in[12];
  const float* en     = (const float*)d_in[13];
  const float* trans  = (const float*)d_in[14];

  char* ws = (char*)d_ws;
  const size_t PRE_OFF  = 0;                          // 131072*200*4 = 104857600
  const size_t EM_OFF   = 104857600;                  // 131072*19*4  = 9961472
  const size_t PART_OFF = EM_OFF + 9961472;           // 1024
  const size_t CNT_OFF  = PART_OFF + 1024;            // 4
  float* PRE  = (float*)(ws + PRE_OFF);
  float* EM   = (float*)(ws + EM_OFF);
  float* PART = (float*)(ws + PART_OFF);
  int*   CNT  = (int*)(ws + CNT_OFF);
  unsigned short* W3 = (unsigned short*)(ws + EM_OFF);  // consumed before k_lin writes EM
  float* out  = (float*)d_out;

  hipMemsetAsync((void*)CNT, 0, sizeof(int), stream);
  k_wprep<<<196, 256, 0, stream>>>(w_ih_f, w_ih_b, W3);
  k_ih<<<512, 256, 0, stream>>>(x, W3, b_ih_f, b_hh_f, b_ih_b, b_hh_b, PRE);
  k_rnn<<<1024, 512, 0, stream>>>(PRE, w_hh_f, w_hh_b);
  k_lin<<<256, 256, 0, stream>>>(PRE, w_lin, b_lin, EM);
  k_crf<<<256, 128, 0, stream>>>(EM, y, st, en, trans, PART, CNT, out);
}

// Round 18
// 578.515 us; speedup vs baseline: 1.6182x; 1.0468x over previous
//
#include <hip/hip_runtime.h>
#include <hip/hip_bf16.h>

#define B_ 256
#define T_ 512
#define IN_ 202
#define HID_ 100
#define K_ 19

typedef __attribute__((ext_vector_type(8))) short short8v;
typedef __attribute__((ext_vector_type(4))) float f32x4;

__device__ __forceinline__ float rl_f(float v, int l) {
  return __int_as_float(__builtin_amdgcn_readlane(__float_as_int(v), l));
}
// register->register broadcast of lane l via LDS crossbar (no storage, no SGPR hazard)
__device__ __forceinline__ float bcast_f(float v, int l) {
  return __int_as_float(__builtin_amdgcn_ds_bpermute(l * 4, __float_as_int(v)));
}
// tanh(x) = 1 - 2/(exp(2x)+1): 5 instrs vs ~25 for libm; exact saturation at +-1.
__device__ __forceinline__ float fast_tanh(float x) {
  float t = __expf(2.f * x);
  float r = __builtin_amdgcn_rcpf(t + 1.f);
  return fmaf(-2.f, r, 1.f);
}

// ---------------- K0: split [wf;wb] (200x202) into 3 exact bf16 planes, padded to 224x224.
__global__ __launch_bounds__(256, 1) void k_wprep(
    const float* __restrict__ wf, const float* __restrict__ wb,
    unsigned short* __restrict__ w3) {
  int idx = blockIdx.x * 256 + threadIdx.x;
  if (idx >= 224 * 224) return;
  int c = idx / 224, k = idx - (idx / 224) * 224;
  float v = 0.f;
  if (k < IN_) {
    if (c < 100) v = wf[c * IN_ + k];
    else if (c < 200) v = wb[(c - 100) * IN_ + k];
  }
  unsigned u0 = __float_as_uint(v) & 0xffff0000u;
  float r1 = v - __uint_as_float(u0);
  unsigned u1 = __float_as_uint(r1) & 0xffff0000u;
  float r2 = r1 - __uint_as_float(u1);
  w3[idx] = (unsigned short)(u0 >> 16);
  w3[50176 + idx] = (unsigned short)(u1 >> 16);
  w3[100352 + idx] = (unsigned short)(__float_as_uint(r2) >> 16);
}

// ---------------- K1: pre = x . [wf;wb]^T + bias via bf16-split MFMA.
// SINGLE PASS over x (was 2 passes): 1024 blocks x 128 rows; wave owns 32 rows
// (2 m-tiles) x ALL 14 n-tiles. acc[2][14] = 112 VGPR (same budget as proven
// 4x7). x staged once per K-chunk (7 chunks, stride-36 proven layout); B planes
// from L2-resident w3. MFMA fragment conventions identical to round-10.
__global__ __launch_bounds__(256, 2) void k_ih(
    const float* __restrict__ x, const unsigned short* __restrict__ w3,
    const float* __restrict__ bif, const float* __restrict__ bhf,
    const float* __restrict__ bib, const float* __restrict__ bhb,
    float* __restrict__ pre) {
  __shared__ float xs[128 * 36];
  __shared__ float bsum[224];
  int tid = threadIdx.x;
  int wv = tid >> 6, l = tid & 63;
  long row0 = (long)blockIdx.x * 128;
  for (int u = tid; u < 224; u += 256) {
    float bv = 0.f;
    if (u < 100) bv = bif[u] + bhf[u];
    else if (u < 200) bv = bib[u - 100] + bhb[u - 100];
    bsum[u] = bv;
  }
  int lr = l & 15;
  int kq = l >> 4;
  f32x4 acc[2][14];
#pragma unroll
  for (int m = 0; m < 2; m++)
#pragma unroll
    for (int n = 0; n < 14; n++) acc[m][n] = (f32x4){0.f, 0.f, 0.f, 0.f};
  for (int ck = 0; ck < 7; ck++) {
    int k0 = ck * 32;
    __syncthreads();
#pragma unroll
    for (int i = 0; i < 8; i++) {
      int u = tid + i * 256;
      int r = u >> 4, kp = u & 15;
      int gk = k0 + 2 * kp;
      float2 v = make_float2(0.f, 0.f);
      if (gk < IN_) v = *(const float2*)(x + (row0 + r) * IN_ + gk);
      *(float2*)(&xs[r * 36 + 2 * kp]) = v;
    }
    __syncthreads();
    // A fragments (2 m-tiles), exact 3-way bf16 split in-register
    short8v A0[2], A1[2], A2[2];
#pragma unroll
    for (int m = 0; m < 2; m++) {
      const float* ap = &xs[(wv * 32 + m * 16 + lr) * 36 + kq * 8];
      float4 fa = *(const float4*)(ap);
      float4 fb = *(const float4*)(ap + 4);
      float f[8] = {fa.x, fa.y, fa.z, fa.w, fb.x, fb.y, fb.z, fb.w};
#pragma unroll
      for (int j = 0; j < 8; j++) {
        unsigned u0 = __float_as_uint(f[j]) & 0xffff0000u;
        float r1 = f[j] - __uint_as_float(u0);
        unsigned u1 = __float_as_uint(r1) & 0xffff0000u;
        float r2 = r1 - __uint_as_float(u1);
        A0[m][j] = (short)(u0 >> 16);
        A1[m][j] = (short)(u1 >> 16);
        A2[m][j] = (short)(__float_as_uint(r2) >> 16);
      }
    }
#pragma unroll
    for (int n = 0; n < 14; n++) {
      int col = n * 16 + lr;
      const unsigned short* bp = w3 + (long)col * 224 + k0 + kq * 8;
      short8v B0 = *(const short8v*)(bp);
      short8v B1 = *(const short8v*)(bp + 50176);
      short8v B2 = *(const short8v*)(bp + 100352);
#pragma unroll
      for (int m = 0; m < 2; m++) {
        f32x4 c = acc[m][n];
        c = __builtin_amdgcn_mfma_f32_16x16x32_bf16(A0[m], B0, c, 0, 0, 0);
        c = __builtin_amdgcn_mfma_f32_16x16x32_bf16(A0[m], B1, c, 0, 0, 0);
        c = __builtin_amdgcn_mfma_f32_16x16x32_bf16(A1[m], B0, c, 0, 0, 0);
        c = __builtin_amdgcn_mfma_f32_16x16x32_bf16(A0[m], B2, c, 0, 0, 0);
        c = __builtin_amdgcn_mfma_f32_16x16x32_bf16(A2[m], B0, c, 0, 0, 0);
        c = __builtin_amdgcn_mfma_f32_16x16x32_bf16(A1[m], B1, c, 0, 0, 0);
        c = __builtin_amdgcn_mfma_f32_16x16x32_bf16(A1[m], B2, c, 0, 0, 0);
        c = __builtin_amdgcn_mfma_f32_16x16x32_bf16(A2[m], B1, c, 0, 0, 0);
        acc[m][n] = c;
      }
    }
  }
#pragma unroll
  for (int m = 0; m < 2; m++) {
    long rbase = row0 + wv * 32 + m * 16 + kq * 4;
#pragma unroll
    for (int n = 0; n < 13; n++) {  // n=13 -> cols 208..223 all padding
      int col = n * 16 + lr;
      if (col < 200) {
        float bv = bsum[col];
#pragma unroll
        for (int r = 0; r < 4; r++)
          pre[(rbase + r) * 200 + col] = acc[m][n][r] + bv;
      }
    }
  }
}

// ---------------- K2: recurrence over b (256 steps); 8 waves per (t,dir) chain.
// K-slices {16,28,28,28}; fast tanh; 2 barriers/step (round-17 proven).
template <int KO, int KN, bool OW>
__device__ __forceinline__ void rnn8(
    float* __restrict__ p, long step, int row, bool owns, int qidx,
    const float* __restrict__ w, float (*hb)[104], float (*ps)[104]) {
  float wr[KN];
#pragma unroll
  for (int i = 0; i < KN / 4; i++) {
    float4 w4 = *(const float4*)(w + row * HID_ + KO + 4 * i);
    wr[4 * i + 0] = w4.x; wr[4 * i + 1] = w4.y;
    wr[4 * i + 2] = w4.z; wr[4 * i + 3] = w4.w;
  }
  float a = 0.f;
  if (OW) a = p[row];
  for (int s = 0; s < B_; s++) {
    int cur = s & 1;
    float a_next = 0.f;
    if (OW && s < B_ - 1) a_next = p[step + row];
    float ac0 = OW ? a : 0.f, ac1 = 0.f, ac2 = 0.f, ac3 = 0.f;
#pragma unroll
    for (int i = 0; i < KN / 4; i++) {
      float4 h4 = *(const float4*)(&hb[cur][KO + 4 * i]);  // uniform -> broadcast
      ac0 = fmaf(h4.x, wr[4 * i + 0], ac0);
      ac1 = fmaf(h4.y, wr[4 * i + 1], ac1);
      ac2 = fmaf(h4.z, wr[4 * i + 2], ac2);
      ac3 = fmaf(h4.w, wr[4 * i + 3], ac3);
    }
    float partial = (ac0 + ac1) + (ac2 + ac3);
    if (!OW && owns) ps[qidx][row] = partial;
    __syncthreads();
    if (OW) {
      float tot = partial + ps[0][row] + ps[1][row] + ps[2][row];
      float hnew = fast_tanh(tot);
      if (owns) {
        p[row] = hnew;
        hb[cur ^ 1][row] = hnew;
      }
    }
    __syncthreads();
    p += step;
    a = a_next;
  }
}

__global__ __launch_bounds__(512, 8) void k_rnn(
    float* __restrict__ pre,
    const float* __restrict__ whf, const float* __restrict__ whb) {
  __shared__ __align__(16) float hb[2][104];
  __shared__ __align__(16) float ps[3][104];
  int bid = blockIdx.x;
  int dir = bid >> 9;
  int t = bid & 511;
  const float* w = dir ? whb : whf;
  int tid = threadIdx.x;
  int wv = tid >> 6, lane = tid & 63;
  int grp = wv & 1;     // 0: rows 0..63, 1: rows 64..99
  int kq = wv >> 1;     // K slice 0..3 (0 = owner)
  int row = grp ? (64 + (lane < 36 ? lane : 35)) : lane;
  bool owns = grp ? (lane < 36) : true;
  long step = dir ? -(long)(T_ * 200) : (long)(T_ * 200);
  float* p = pre + ((long)(dir ? (B_ - 1) : 0) * T_ + t) * 200 + dir * 100;
  if (tid < 104) hb[0][tid] = 0.f;
  __syncthreads();
  if (kq == 0)      rnn8<0, 16, true >(p, step, row, owns, 0, w, hb, ps);
  else if (kq == 1) rnn8<16, 28, false>(p, step, row, owns, 0, w, hb, ps);
  else if (kq == 2) rnn8<44, 28, false>(p, step, row, owns, 1, w, hb, ps);
  else              rnn8<72, 28, false>(p, step, row, owns, 2, w, hb, ps);
}

// ---------------- K3: logits = h @ w_lin^T + b_lin ; softmax over 19. 2 rows/thread.
__global__ __launch_bounds__(256, 4) void k_lin(
    const float* __restrict__ h, const float* __restrict__ wlin,
    const float* __restrict__ blin, float* __restrict__ em) {
  int tid = threadIdx.x;
  long r0 = ((long)blockIdx.x * 256 + tid) * 2;
  const float* h0 = h + r0 * 200;
  float acc0[K_], acc1[K_];
#pragma unroll
  for (int c = 0; c < K_; c++) { float bb = blin[c]; acc0[c] = bb; acc1[c] = bb; }
  for (int kk = 0; kk < 50; kk++) {
    float4 a = *(const float4*)(h0 + 4 * kk);
    float4 b = *(const float4*)(h0 + 200 + 4 * kk);
#pragma unroll
    for (int c = 0; c < K_; c++) {
      float4 wv = *(const float4*)(wlin + c * 200 + 4 * kk);
      acc0[c] += a.x * wv.x + a.y * wv.y + a.z * wv.z + a.w * wv.w;
      acc1[c] += b.x * wv.x + b.y * wv.y + b.z * wv.z + b.w * wv.w;
    }
  }
  float mx0 = acc0[0], mx1 = acc1[0];
#pragma unroll
  for (int c = 1; c < K_; c++) { mx0 = fmaxf(mx0, acc0[c]); mx1 = fmaxf(mx1, acc1[c]); }
  float s0 = 0.f, s1 = 0.f;
#pragma unroll
  for (int c = 0; c < K_; c++) {
    acc0[c] = __expf(acc0[c] - mx0); s0 += acc0[c];
    acc1[c] = __expf(acc1[c] - mx1); s1 += acc1[c];
  }
  float i0 = 1.f / s0, i1 = 1.f / s1;
  float* e0 = em + r0 * K_;
#pragma unroll
  for (int c = 0; c < K_; c++) { e0[c] = acc0[c] * i0; e0[K_ + c] = acc1[c] * i1; }
}

// ---------------- K4: 2 waves per b; bpermute state broadcast (round-15 proven).
__global__ __launch_bounds__(128, 1) void k_crf(
    const float* __restrict__ em, const int* __restrict__ y,
    const float* __restrict__ st_g, const float* __restrict__ en_g,
    const float* __restrict__ tr_g,
    float* __restrict__ part, int* __restrict__ cnt,
    float* __restrict__ out) {
  __shared__ __align__(16) float es[T_ * K_];
  __shared__ int ys[T_];
  __shared__ float trs[K_ * K_];
  __shared__ float st[K_], en[K_];
  __shared__ unsigned char hl[511 * K_ + 13];
  int b = blockIdx.x;
  int tid = threadIdx.x;
  int wv = tid >> 6, lane = tid & 63;
  const float4* eb4 = (const float4*)(em + (long)b * T_ * K_);
  for (int u = tid; u < T_ * K_ / 4; u += 128) ((float4*)es)[u] = eb4[u];
  for (int u = tid; u < T_; u += 128) ys[u] = y[b * T_ + u];
  for (int u = tid; u < K_ * K_; u += 128) trs[u] = tr_g[u];
  if (tid < K_) { st[tid] = st_g[tid]; en[tid] = en_g[tid]; }
  __syncthreads();
  int lmin = T_;
  for (int u = lane; u < T_; u += 64)
    if (ys[u] == -1 && u < lmin) lmin = u;
#pragma unroll
  for (int off = 32; off; off >>= 1) {
    int o = __shfl_xor(lmin, off, 64);
    lmin = lmin < o ? lmin : o;
  }
  int len = lmin;  // >= 1

  int jj = lane < K_ ? lane : K_ - 1;
  bool act = lane < K_;
  float enr[20];
#pragma unroll
  for (int q = 0; q < 5; q++) {
    float4 e4 = (q < 4) ? *(const float4*)(&en[4 * q])
                        : make_float4(en[16], en[17], en[18], -1e30f);
    enr[4 * q] = e4.x; enr[4 * q + 1] = e4.y; enr[4 * q + 2] = e4.z; enr[4 * q + 3] = e4.w;
  }

  if (wv == 0) {
    float gacc = 0.f;
    for (int t = 1 + lane; t < len; t += 64)
      gacc += trs[ys[t - 1] * K_ + ys[t]] + es[t * K_ + ys[t]];
#pragma unroll
    for (int off = 32; off; off >>= 1) gacc += __shfl_xor(gacc, off, 64);
    int y0 = ys[0], ylast = ys[len - 1];
    float num = st[y0] + es[y0] + gacc + en[ylast];
    float Ecol[K_];
#pragma unroll
    for (int i = 0; i < K_; i++) Ecol[i] = __expf(trs[i * K_ + jj]);
    float P = __expf(st[jj] + es[jj]);
    int kacc = 0;
    float ee = __expf(es[K_ + jj]);
    for (int t = 1; t < len; t++) {
      float pr[K_];
#pragma unroll
      for (int i = 0; i < K_; i++) pr[i] = bcast_f(P, i);
      int tn = (t + 1 < T_) ? t + 1 : T_ - 1;
      float e_next = es[tn * K_ + jj];
      unsigned pb = __float_as_uint(pr[0]);
      int ex = (int)((pb >> 23) & 0xff);
      float scale = __uint_as_float((unsigned)(254 - ex) << 23);
      kacc += ex - 127;
      float a0 = 0.f, a1 = 0.f, a2 = 0.f, a3 = 0.f;
#pragma unroll
      for (int i = 0; i < K_; i++) {
        if ((i & 3) == 0)      a0 = fmaf(pr[i], Ecol[i], a0);
        else if ((i & 3) == 1) a1 = fmaf(pr[i], Ecol[i], a1);
        else if ((i & 3) == 2) a2 = fmaf(pr[i], Ecol[i], a2);
        else                   a3 = fmaf(pr[i], Ecol[i], a3);
      }
      P = (((a0 + a1) + (a2 + a3)) * ee) * scale;
      ee = __expf(e_next);
    }
    {
      float pr[K_];
#pragma unroll
      for (int i = 0; i < K_; i++) pr[i] = bcast_f(P, i);
      float sm = 0.f;
#pragma unroll
      for (int i = 0; i < K_; i++) sm += pr[i] * __expf(enr[i]);
      if (lane == 0) part[b] = __logf(sm) + (float)kacc * 0.6931471805599453f - num;
    }
    int old = -1;
    if (lane == 0) { __threadfence(); old = atomicAdd(cnt, 1); }
    old = __shfl(old, 0, 64);
    if (old == B_ - 1) {
      __threadfence();
      float s = 0.f;
      for (int u = lane; u < B_; u += 64) s += part[u];
#pragma unroll
      for (int off = 32; off; off >>= 1) s += __shfl_xor(s, off, 64);
      if (lane == 0) out[0] = s;
    }
  } else {
    float Tt[K_];
#pragma unroll
    for (int i = 0; i < K_; i++) Tt[i] = trs[i * K_ + jj];
    float V = st[jj] + es[jj];
    float e = es[K_ + jj];
    for (int t = 1; t < len; t++) {
      float vr[K_];
#pragma unroll
      for (int i = 0; i < K_; i++) vr[i] = bcast_f(V, i);
      int tn = (t + 1 < T_) ? t + 1 : T_ - 1;
      float e_next = es[tn * K_ + jj];
      float b0 = -1e30f, b1 = -1e30f, b2 = -1e30f, b3 = -1e30f;
      int a0 = 0, a1 = 5, a2 = 10, a3 = 15;
#pragma unroll
      for (int i = 0; i < 5; i++)  { float c = vr[i] + Tt[i]; if (c > b0) { b0 = c; a0 = i; } }
#pragma unroll
      for (int i = 5; i < 10; i++) { float c = vr[i] + Tt[i]; if (c > b1) { b1 = c; a1 = i; } }
#pragma unroll
      for (int i = 10; i < 15; i++){ float c = vr[i] + Tt[i]; if (c > b2) { b2 = c; a2 = i; } }
#pragma unroll
      for (int i = 15; i < 19; i++){ float c = vr[i] + Tt[i]; if (c > b3) { b3 = c; a3 = i; } }
      if (b1 > b0) { b0 = b1; a0 = a1; }
      if (b2 > b0) { b0 = b2; a0 = a2; }
      if (b3 > b0) { b0 = b3; a0 = a3; }
      if (act) hl[(t - 1) * K_ + lane] = (unsigned char)a0;
      V = b0 + e;
      e = e_next;
    }
    int aa;
    {
      float vr[K_];
#pragma unroll
      for (int i = 0; i < K_; i++) vr[i] = bcast_f(V, i);
      float bb = vr[0] + enr[0]; aa = 0;
#pragma unroll
      for (int i = 1; i < K_; i++) {
        float c = vr[i] + enr[i];
        if (c > bb) { bb = c; aa = i; }
      }
    }
    float* ob = out + 1 + (long)b * T_;
    for (int u = lane; u < T_; u += 64)
      if (u >= len) ob[u] = -1.f;
    int tag = aa;
    if (lane == 0) ob[len - 1] = (float)tag;
    int vc = (act && len >= 2) ? (int)hl[(len - 2) * K_ + lane] : 0;
    for (int ti = len - 2; ti >= 0; ti--) {
      int vn = 0;
      if (ti > 0 && act) vn = (int)hl[(ti - 1) * K_ + lane];
      int ts = __builtin_amdgcn_readfirstlane(tag);
      tag = __builtin_amdgcn_readlane(vc, ts);
      if (lane == 0) ob[ti] = (float)tag;
      vc = vn;
    }
  }
}

extern "C" void kernel_launch(void* const* d_in, const int* in_sizes, int n_in,
                              void* d_out, int out_size, void* d_ws, size_t ws_size,
                              hipStream_t stream) {
  const float* x      = (const float*)d_in[0];
  const int*   y      = (const int*)d_in[1];
  const float* w_ih_f = (const float*)d_in[2];
  const float* w_hh_f = (const float*)d_in[3];
  const float* b_ih_f = (const float*)d_in[4];
  const float* b_hh_f = (const float*)d_in[5];
  const float* w_ih_b = (const float*)d_in[6];
  const float* w_hh_b = (const float*)d_in[7];
  const float* b_ih_b = (const float*)d_in[8];
  const float* b_hh_b = (const float*)d_in[9];
  const float* w_lin  = (const float*)d_in[10];
  const float* b_lin  = (const float*)d_in[11];
  const float* st     = (const float*)d_in[12];
  const float* en     = (const float*)d_in[13];
  const float* trans  = (const float*)d_in[14];

  char* ws = (char*)d_ws;
  const size_t PRE_OFF  = 0;                          // 131072*200*4 = 104857600
  const size_t EM_OFF   = 104857600;                  // 131072*19*4  = 9961472
  const size_t PART_OFF = EM_OFF + 9961472;           // 1024
  const size_t CNT_OFF  = PART_OFF + 1024;            // 4
  float* PRE  = (float*)(ws + PRE_OFF);
  float* EM   = (float*)(ws + EM_OFF);
  float* PART = (float*)(ws + PART_OFF);
  int*   CNT  = (int*)(ws + CNT_OFF);
  unsigned short* W3 = (unsigned short*)(ws + EM_OFF);  // consumed before k_lin writes EM
  float* out  = (float*)d_out;

  hipMemsetAsync((void*)CNT, 0, sizeof(int), stream);
  k_wprep<<<196, 256, 0, stream>>>(w_ih_f, w_ih_b, W3);
  k_ih<<<1024, 256, 0, stream>>>(x, W3, b_ih_f, b_hh_f, b_ih_b, b_hh_b, PRE);
  k_rnn<<<1024, 512, 0, stream>>>(PRE, w_hh_f, w_hh_b);
  k_lin<<<256, 256, 0, stream>>>(PRE, w_lin, b_lin, EM);
  k_crf<<<256, 128, 0, stream>>>(EM, y, st, en, trans, PART, CNT, out);
}